// Round 8
// baseline (351.011 us; speedup 1.0000x reference)
//
#include <hip/hip_runtime.h>
#include <hip/hip_bf16.h>

// Problem constants (fixed by the reference)
#define NN 100000
#define NE 1600000
#define NG 64
#define FD 64
#define EPSV 1e-5f

typedef __hip_bfloat16 bf16;
typedef __attribute__((ext_vector_type(8))) short bf16x8;  // 8 bf16 = 4 VGPRs (MFMA A/B frag)
typedef __attribute__((ext_vector_type(4))) float f32x4;   // MFMA C/D frag

__device__ __forceinline__ float ldb(bf16 v) { return __bfloat162float(v); }
__device__ __forceinline__ bf16 f2b(float v) { return __float2bfloat16(v); }
__device__ __forceinline__ float b2f_bits(short s) {   // exact bf16 -> fp32
    return __uint_as_float(((unsigned)(unsigned short)s) << 16);
}

// ---------------- counting-sort CSR build parameters ----------------
// R13/R14: 2-level LDS counting sort. R15: persistent-wave register-resident GEMM.
// R16: hop row-pairs. R17: H planes (write fix) but R=4 serialized at 44 VGPR (default
// occupancy heuristic) -> regressed. R18: revert to 2-row on planes (42us, 43% of BW,
// latency-bound; WRITE back to 2x: 256B dirty < 512B writeback granule).
// R19: hops 2/3 -> hop4_kernel: 4 rows/wave with __launch_bounds__(256,4) (128 VGPR
// budget so the compiler KEEPS 12 gathers in flight — R18 proved it hoists when the
// budget allows), named scalars, int4 meta loads, 512B contiguous stores. Hop1 stays
// 2-row (FIRST's dis-gathers+writebacks won't fit 128 VGPR at R=4).
#define NB1 391                      // coarse buckets (dst>>8), 100000/256 -> 0..390
#define CB 625                       // coarse blocks
#define EPB 2560                     // edges per coarse block (CB*EPB == NE exactly)
#define CCN (NB1 * CB)               // count-matrix entries = 244375
#define SCB2 ((CCN + 2047) / 2048)   // scan blocks over count matrix = 120

// bijective chunked XCD swizzle (m204 variant): consecutive logical blocks -> same XCD
__device__ __forceinline__ int xcd_chunk(int bid, int nwg) {
    int q = nwg >> 3, r = nwg & 7;
    int xcd = bid & 7, j = bid >> 3;
    return (xcd < r ? xcd * (q + 1) : r * (q + 1) + (xcd - r) * q) + j;
}

// ---------------- workspace layout (bytes) ----------------
constexpr size_t ALGN(size_t x) { return (x + 255) & ~(size_t)255; }
constexpr size_t OFF_GSUM = 0;                                         // float[NG*FD]
constexpr size_t OFF_GSSQ = OFF_GSUM + ALGN((size_t)NG * FD * 4);      // float[NG*FD]
constexpr size_t OFF_GCNT = OFF_GSSQ + ALGN((size_t)NG * FD * 4);      // float[NG]
constexpr size_t OFF_PSUM = OFF_GCNT + ALGN((size_t)NG * 4);           // float[NG*FD]
constexpr size_t OFF_PMAX = OFF_PSUM + ALGN((size_t)NG * FD * 4);      // int[NG*FD] (relu>=0 so 0-init ok)
constexpr size_t ZERO_BYTES = OFF_PMAX + ALGN((size_t)NG * FD * 4);    // everything above memset(0)
constexpr size_t OFF_CNT  = ZERO_BYTES;                                // int[NN] (written by fine)
constexpr size_t OFF_DIS  = OFF_CNT  + ALGN((size_t)NN * 4);           // float[NN]
constexpr size_t OFF_ROWP = OFF_DIS  + ALGN((size_t)NN * 4);           // int[NN]
constexpr size_t OFF_BSUM = OFF_ROWP + ALGN((size_t)NN * 4);           // int[256] scan block totals
constexpr size_t OFF_WT   = OFF_BSUM + ALGN(256 * 4);                  // bf16[64][256] W^T stacked
constexpr size_t OFF_CSR  = OFF_WT   + ALGN(16384 * 2);                // int2[NE] final {src, w-bits}
constexpr size_t OFF_H    = OFF_CSR  + ALGN((size_t)NE * 8);           // bf16[4][NN][64] planes x|h1|h2|h3
constexpr size_t OFF_OUT  = OFF_H    + ALGN((size_t)NN * 256 * 2);     // float[NN*FD]
// aliases inside the OUT region (all dead before gemm):
constexpr size_t OFF_CSRT = OFF_OUT;                                   // int2[NE] {src|fine<<17, w}
constexpr size_t OFF_CC   = OFF_CSRT + ALGN((size_t)NE * 8);           // int[NB1*CB] count/scan matrix
static_assert(OFF_CC + (size_t)CCN * 4 - OFF_OUT <= (size_t)NN * FD * 4, "alias overflow");

// ---------------- phase 1: coarse LDS histogram + xcopy/wt streaming ----------------
#define XCB 6250   // NN*64 f32 -> bf16, 4 elems/thread: 6.4M/1024
__global__ __launch_bounds__(256) void coarse_fused_kernel(const int* __restrict__ dst,
                                                           int* __restrict__ cc,
                                                           const float* __restrict__ x,
                                                           bf16* __restrict__ H,
                                                           const float* __restrict__ W,
                                                           bf16* __restrict__ Wt) {
    int b = blockIdx.x;
    if (b < CB) {
        __shared__ int hist[NB1];
        for (int i = threadIdx.x; i < NB1; i += 256) hist[i] = 0;
        __syncthreads();
        int e0 = b * EPB + threadIdx.x;
        #pragma unroll
        for (int i = 0; i < EPB / 256; i++)
            atomicAdd(&hist[dst[e0 + i * 256] >> 8], 1);   // LDS atomic, rare conflicts
        __syncthreads();
        for (int i = threadIdx.x; i < NB1; i += 256)
            cc[(size_t)i * CB + b] = hist[i];              // [bucket][block] matrix
    } else if (b < CB + XCB) {
        // x (f32) -> plane0 (bf16), fully linear stream, 4 elems/thread
        int i = (b - CB) * 256 + threadIdx.x;              // 0 .. NN*64/4-1 exact
        float4 xv = ((const float4*)x)[i];
        bf16 t0 = f2b(xv.x), t1 = f2b(xv.y), t2 = f2b(xv.z), t3 = f2b(xv.w);
        ushort4 o;
        o.x = *(unsigned short*)&t0; o.y = *(unsigned short*)&t1;
        o.z = *(unsigned short*)&t2; o.w = *(unsigned short*)&t3;
        ((ushort4*)H)[i] = o;
    } else {
        int i = (b - CB - XCB) * 256 + threadIdx.x;  // 0..16383
        int n = i & 63, kk = i >> 6;
        Wt[n * 256 + kk] = f2b(W[kk * 64 + n]);
    }
}

// ---------------- scan of the count matrix (bucket-major => global offsets) ----------
#define SCAN_BLK 256
#define SCAN_ITEMS 8   // 2048 elems per block
__global__ __launch_bounds__(SCAN_BLK) void scan_blocks(int* __restrict__ data,
                                                        int* __restrict__ bsum, int n) {
    __shared__ int lds[SCAN_BLK];
    int t = threadIdx.x, b = blockIdx.x;
    int base = b * SCAN_BLK * SCAN_ITEMS + t * SCAN_ITEMS;
    int v[SCAN_ITEMS];
    int s = 0;
    #pragma unroll
    for (int i = 0; i < SCAN_ITEMS; i++) {
        int idx = base + i;
        v[i] = (idx < n) ? data[idx] : 0;
        s += v[i];
    }
    lds[t] = s;
    __syncthreads();
    for (int off = 1; off < SCAN_BLK; off <<= 1) {
        int x = (t >= off) ? lds[t - off] : 0;
        __syncthreads();
        lds[t] += x;
        __syncthreads();
    }
    int excl = lds[t] - s;
    if (t == SCAN_BLK - 1) bsum[b] = lds[t];   // per-block TOTAL
    int run = excl;
    #pragma unroll
    for (int i = 0; i < SCAN_ITEMS; i++) {
        int idx = base + i;
        if (idx < n) data[idx] = run;          // in-place: own range only, reads done
        run += v[i];
    }
}

// single-block exclusive scan of the <=256 per-block totals
__global__ __launch_bounds__(256) void bsum_scan(int* __restrict__ bsum, int nb) {
    __shared__ int lds[256];
    int t = threadIdx.x;
    int v = (t < nb) ? bsum[t] : 0;
    lds[t] = v;
    __syncthreads();
    for (int off = 1; off < 256; off <<= 1) {
        int x = (t >= off) ? lds[t - off] : 0;
        __syncthreads();
        lds[t] += x;
        __syncthreads();
    }
    if (t < nb) bsum[t] = lds[t] - v;   // exclusive prefix of totals
}

__global__ __launch_bounds__(256) void scan_add2(int* __restrict__ data,
                                                 const int* __restrict__ bpref, int n) {
    int i = blockIdx.x * 256 + threadIdx.x;
    if (i >= n) return;
    data[i] += bpref[i >> 11];
}

// ---------------- phase 3: LDS-sorted coarse scatter, coalesced write-out ------------
__global__ __launch_bounds__(256) void scatter2_kernel(const int* __restrict__ src,
                                                       const int* __restrict__ dst,
                                                       const float* __restrict__ ew,
                                                       const int* __restrict__ cc,
                                                       int2* __restrict__ csrt) {
    __shared__ int sc[512];        // bucket counts -> inclusive prefix (padded to 512)
    __shared__ int gdel[NB1];      // global_start - local_start per bucket
    __shared__ int2 stage[EPB];    // block's edges in bucket order
    __shared__ int sdel[EPB];      // per-slot global delta
    int t = threadIdx.x;
    int L = xcd_chunk(blockIdx.x, CB);   // adjacent logical blocks -> same XCD

    sc[t] = 0; sc[t + 256] = 0;
    __syncthreads();

    int br[EPB / 256], px[EPB / 256], pw[EPB / 256];
    #pragma unroll
    for (int i = 0; i < EPB / 256; i++) {
        int e = L * EPB + i * 256 + t;
        int d = dst[e];
        int bk = d >> 8;
        int rk = atomicAdd(&sc[bk], 1);            // local rank within (bucket, block)
        br[i] = bk | (rk << 9);                    // bk<512 (9b), rk<2560 (12b)
        px[i] = src[e] | ((d & 255) << 17);        // src<2^17, fine dst bits 17..24
        pw[i] = __float_as_int(ew[e]);
    }
    __syncthreads();

    // inclusive scan of sc[0..511], 2 slots/thread Hillis-Steele
    for (int off = 1; off < 512; off <<= 1) {
        int a0 = (t >= off) ? sc[t - off] : 0;
        int a1 = sc[t + 256 - off];                // t+256 >= 256 >= off always
        __syncthreads();
        sc[t] += a0; sc[t + 256] += a1;
        __syncthreads();
    }

    for (int i = t; i < NB1; i += 256)
        gdel[i] = cc[(size_t)i * CB + L] - ((i > 0) ? sc[i - 1] : 0);
    __syncthreads();

    #pragma unroll
    for (int i = 0; i < EPB / 256; i++) {
        int bk = br[i] & 511;
        int rk = br[i] >> 9;
        int slot = ((bk > 0) ? sc[bk - 1] : 0) + rk;
        stage[slot] = make_int2(px[i], pw[i]);
        sdel[slot] = gdel[bk];
    }
    __syncthreads();

    for (int j = t; j < EPB; j += 256)             // coalesced runs out
        csrt[(size_t)(sdel[j] + j)] = stage[j];
}

// ---------------- phase 4: per-bucket fine sort + rowp/cnts/dis emission ------------
__global__ __launch_bounds__(256) void fine_kernel(const int* __restrict__ cc,
                                                   const int2* __restrict__ csrt,
                                                   int2* __restrict__ csr,
                                                   int* __restrict__ rowp,
                                                   int* __restrict__ cnts,
                                                   float* __restrict__ dis) {
    __shared__ int hist[256];
    __shared__ float degw[256];
    __shared__ int pref[256];
    __shared__ int fcur[256];
    int b = blockIdx.x;
    int t = threadIdx.x;
    int base = cc[(size_t)b * CB];
    int end = (b == NB1 - 1) ? NE : cc[(size_t)(b + 1) * CB];
    int cnt = end - base;
    hist[t] = 0; degw[t] = 0.f;
    __syncthreads();
    for (int j = t; j < cnt; j += 256) {
        int2 e = csrt[base + j];
        int f = e.x >> 17;
        atomicAdd(&hist[f], 1);
        atomicAdd(&degw[f], __int_as_float(e.y));  // deg = sum of raw w per dst row
    }
    __syncthreads();
    int hv = hist[t];
    pref[t] = hv;
    __syncthreads();
    for (int off = 1; off < 256; off <<= 1) {
        int x = (t >= off) ? pref[t - off] : 0;
        __syncthreads();
        pref[t] += x;
        __syncthreads();
    }
    int ex = pref[t] - hv;                  // exclusive fine prefix
    fcur[t] = ex;
    int node = b * 256 + t;
    if (node < NN) {
        rowp[node] = base + ex;
        cnts[node] = hv;
        float s = degw[t];
        dis[node] = (s > 0.f) ? rsqrtf(s) : 0.f;
    }
    __syncthreads();
    for (int j = t; j < cnt; j += 256) {    // 2nd read hits L2 (33KB slice)
        int2 e = csrt[base + j];
        int f = e.x >> 17;
        int pos = atomicAdd(&fcur[f], 1);   // LDS atomic
        csr[base + pos] = make_int2(e.x & 0x1FFFF, e.y);
    }
}

// ---------------- hop: wide-vector gather, plane layout ----------------
// hin/hout are planes [NN][64]. FIRST: csr.y holds RAW w -> gather dis[e.x],
// nr = w*dis[src], write back so hops 2/3 read pre-scaled.
template <bool FIRST>
__device__ __forceinline__ void row_accum_gen(const bf16* __restrict__ hin,
                                              int2* cp, int cnt,
                                              const float* __restrict__ dis,
                                              int sub, int fl, float a[8]) {
    if (cnt <= 24) {
        int2 e0 = (sub < cnt) ? cp[sub] : make_int2(0, 0);
        int2 e1 = (8 + sub < cnt) ? cp[8 + sub] : make_int2(0, 0);
        int2 e2 = (16 + sub < cnt) ? cp[16 + sub] : make_int2(0, 0);
        bf16x8 v0 = *(const bf16x8*)(hin + (size_t)e0.x * 64 + fl * 8);
        bf16x8 v1 = *(const bf16x8*)(hin + (size_t)e1.x * 64 + fl * 8);
        bf16x8 v2 = *(const bf16x8*)(hin + (size_t)e2.x * 64 + fl * 8);
        float w0 = __int_as_float(e0.y);
        float w1 = __int_as_float(e1.y);
        float w2 = __int_as_float(e2.y);
        if (FIRST) {
            w0 *= dis[e0.x]; w1 *= dis[e1.x]; w2 *= dis[e2.x];
            if (fl == 0) {
                if (sub < cnt)      cp[sub].y      = __float_as_int(w0);
                if (8 + sub < cnt)  cp[8 + sub].y  = __float_as_int(w1);
                if (16 + sub < cnt) cp[16 + sub].y = __float_as_int(w2);
            }
        }
        #pragma unroll
        for (int i = 0; i < 8; i++)
            a[i] += w0 * b2f_bits(v0[i]) + w1 * b2f_bits(v1[i]) + w2 * b2f_bits(v2[i]);
    } else {
        float b[8] = {0, 0, 0, 0, 0, 0, 0, 0};
        int j = 0;
        for (; j + 16 <= cnt; j += 16) {
            int2 e0 = cp[j + sub];
            int2 e1 = cp[j + 8 + sub];
            bf16x8 v0 = *(const bf16x8*)(hin + (size_t)e0.x * 64 + fl * 8);
            bf16x8 v1 = *(const bf16x8*)(hin + (size_t)e1.x * 64 + fl * 8);
            float w0 = __int_as_float(e0.y);
            float w1 = __int_as_float(e1.y);
            if (FIRST) {
                w0 *= dis[e0.x]; w1 *= dis[e1.x];
                if (fl == 0) {
                    cp[j + sub].y     = __float_as_int(w0);
                    cp[j + 8 + sub].y = __float_as_int(w1);
                }
            }
            #pragma unroll
            for (int i = 0; i < 8; i++) a[i] += w0 * b2f_bits(v0[i]);
            #pragma unroll
            for (int i = 0; i < 8; i++) b[i] += w1 * b2f_bits(v1[i]);
        }
        for (; j < cnt; j += 8) {
            int jj = j + sub;
            int2 e = (jj < cnt) ? cp[jj] : make_int2(0, 0);
            bf16x8 v = *(const bf16x8*)(hin + (size_t)e.x * 64 + fl * 8);
            float w = __int_as_float(e.y);
            if (FIRST) {
                w *= dis[e.x];
                if (fl == 0 && jj < cnt) cp[jj].y = __float_as_int(w);
            }
            #pragma unroll
            for (int i = 0; i < 8; i++) a[i] += w * b2f_bits(v[i]);
        }
        #pragma unroll
        for (int i = 0; i < 8; i++) a[i] += b[i];
    }
}

// 2-row hop (used for hop1/FIRST; proven 28-VGPR structure)
template <bool FIRST>
__global__ __launch_bounds__(256) void hop_kernel(const bf16* __restrict__ hin,  // plane k-1
                                                  bf16* __restrict__ hout,       // plane k
                                                  const int* __restrict__ rowp,
                                                  const int* __restrict__ cnts,
                                                  int2* __restrict__ csr,
                                                  const float* __restrict__ dis) {
    int pair = blockIdx.x * 4 + (threadIdx.x >> 6);
    int rowA = pair * 2;
    if (rowA >= NN) return;
    rowA = __builtin_amdgcn_readfirstlane(rowA);
    int rowB = rowA + 1;                     // NN even -> always valid
    int lane = threadIdx.x & 63;
    int sub = lane >> 3;   // edge slot 0..7
    int fl = lane & 7;     // feature octet 0..7

    int stA = rowp[rowA], cnA = cnts[rowA];
    int stB = rowp[rowB], cnB = cnts[rowB];
    float drA = dis[rowA], drB = dis[rowB];
    int2* cpA = csr + stA;
    int2* cpB = csr + stB;

    float a[8] = {0, 0, 0, 0, 0, 0, 0, 0};
    float c[8] = {0, 0, 0, 0, 0, 0, 0, 0};

    if (cnA <= 24 && cnB <= 24) {
        int2 eA0 = (sub < cnA) ? cpA[sub] : make_int2(0, 0);
        int2 eA1 = (8 + sub < cnA) ? cpA[8 + sub] : make_int2(0, 0);
        int2 eA2 = (16 + sub < cnA) ? cpA[16 + sub] : make_int2(0, 0);
        int2 eB0 = (sub < cnB) ? cpB[sub] : make_int2(0, 0);
        int2 eB1 = (8 + sub < cnB) ? cpB[8 + sub] : make_int2(0, 0);
        int2 eB2 = (16 + sub < cnB) ? cpB[16 + sub] : make_int2(0, 0);
        const bf16* hf = hin + fl * 8;
        bf16x8 vA0 = *(const bf16x8*)(hf + (size_t)eA0.x * 64);
        bf16x8 vA1 = *(const bf16x8*)(hf + (size_t)eA1.x * 64);
        bf16x8 vA2 = *(const bf16x8*)(hf + (size_t)eA2.x * 64);
        bf16x8 vB0 = *(const bf16x8*)(hf + (size_t)eB0.x * 64);
        bf16x8 vB1 = *(const bf16x8*)(hf + (size_t)eB1.x * 64);
        bf16x8 vB2 = *(const bf16x8*)(hf + (size_t)eB2.x * 64);
        float wA0 = __int_as_float(eA0.y);
        float wA1 = __int_as_float(eA1.y);
        float wA2 = __int_as_float(eA2.y);
        float wB0 = __int_as_float(eB0.y);
        float wB1 = __int_as_float(eB1.y);
        float wB2 = __int_as_float(eB2.y);
        if (FIRST) {
            wA0 *= dis[eA0.x]; wA1 *= dis[eA1.x]; wA2 *= dis[eA2.x];
            wB0 *= dis[eB0.x]; wB1 *= dis[eB1.x]; wB2 *= dis[eB2.x];
            if (fl == 0) {
                if (sub < cnA)      cpA[sub].y      = __float_as_int(wA0);
                if (8 + sub < cnA)  cpA[8 + sub].y  = __float_as_int(wA1);
                if (16 + sub < cnA) cpA[16 + sub].y = __float_as_int(wA2);
                if (sub < cnB)      cpB[sub].y      = __float_as_int(wB0);
                if (8 + sub < cnB)  cpB[8 + sub].y  = __float_as_int(wB1);
                if (16 + sub < cnB) cpB[16 + sub].y = __float_as_int(wB2);
            }
        }
        #pragma unroll
        for (int i = 0; i < 8; i++) {
            a[i] = wA0 * b2f_bits(vA0[i]) + wA1 * b2f_bits(vA1[i]) + wA2 * b2f_bits(vA2[i]);
            c[i] = wB0 * b2f_bits(vB0[i]) + wB1 * b2f_bits(vB1[i]) + wB2 * b2f_bits(vB2[i]);
        }
    } else {
        row_accum_gen<FIRST>(hin, cpA, cnA, dis, sub, fl, a);
        row_accum_gen<FIRST>(hin, cpB, cnB, dis, sub, fl, c);
    }

    #pragma unroll
    for (int i = 0; i < 8; i++) { a[i] += __shfl_xor(a[i], 8);  c[i] += __shfl_xor(c[i], 8); }
    #pragma unroll
    for (int i = 0; i < 8; i++) { a[i] += __shfl_xor(a[i], 16); c[i] += __shfl_xor(c[i], 16); }
    #pragma unroll
    for (int i = 0; i < 8; i++) { a[i] += __shfl_xor(a[i], 32); c[i] += __shfl_xor(c[i], 32); }

    if (sub == 0) {
        bf16x8 ovA, ovB;
        #pragma unroll
        for (int i = 0; i < 8; i++) {
            bf16 tA = f2b(a[i] * drA);
            bf16 tB = f2b(c[i] * drB);
            ovA[i] = *(short*)&tA;
            ovB[i] = *(short*)&tB;
        }
        *(bf16x8*)(hout + (size_t)rowA * 64 + fl * 8) = ovA;
        *(bf16x8*)(hout + (size_t)rowB * 64 + fl * 8) = ovB;
    }
}

// 4-row hop for hops 2/3: __launch_bounds__(256,4) -> 128 VGPR budget so all 12
// gathers stay hoisted (R17's 44-VGPR serialization was the default heuristic).
__global__ __launch_bounds__(256, 4) void hop4_kernel(const bf16* __restrict__ hin,
                                                      bf16* __restrict__ hout,
                                                      const int* __restrict__ rowp,
                                                      const int* __restrict__ cnts,
                                                      int2* __restrict__ csr,
                                                      const float* __restrict__ dis) {
    int quad = blockIdx.x * 4 + (threadIdx.x >> 6);
    int r0 = quad * 4;
    if (r0 >= NN) return;
    r0 = __builtin_amdgcn_readfirstlane(r0);   // NN % 4 == 0 -> all 4 rows valid
    int lane = threadIdx.x & 63;
    int sub = lane >> 3;
    int fl = lane & 7;

    int4 st = *(const int4*)(rowp + r0);       // 16B-aligned (r0 % 4 == 0)
    int4 cn = *(const int4*)(cnts + r0);
    float4 dr = *(const float4*)(dis + r0);
    int2* cpA = csr + st.x;
    int2* cpB = csr + st.y;
    int2* cpC = csr + st.z;
    int2* cpD = csr + st.w;

    float a[8] = {0, 0, 0, 0, 0, 0, 0, 0};
    float c[8] = {0, 0, 0, 0, 0, 0, 0, 0};
    float d[8] = {0, 0, 0, 0, 0, 0, 0, 0};
    float g[8] = {0, 0, 0, 0, 0, 0, 0, 0};

    if (cn.x <= 24 && cn.y <= 24 && cn.z <= 24 && cn.w <= 24) {
        // 12 edge loads issue together, then 12 gathers together
        int2 eA0 = (sub < cn.x) ? cpA[sub] : make_int2(0, 0);
        int2 eA1 = (8 + sub < cn.x) ? cpA[8 + sub] : make_int2(0, 0);
        int2 eA2 = (16 + sub < cn.x) ? cpA[16 + sub] : make_int2(0, 0);
        int2 eB0 = (sub < cn.y) ? cpB[sub] : make_int2(0, 0);
        int2 eB1 = (8 + sub < cn.y) ? cpB[8 + sub] : make_int2(0, 0);
        int2 eB2 = (16 + sub < cn.y) ? cpB[16 + sub] : make_int2(0, 0);
        int2 eC0 = (sub < cn.z) ? cpC[sub] : make_int2(0, 0);
        int2 eC1 = (8 + sub < cn.z) ? cpC[8 + sub] : make_int2(0, 0);
        int2 eC2 = (16 + sub < cn.z) ? cpC[16 + sub] : make_int2(0, 0);
        int2 eD0 = (sub < cn.w) ? cpD[sub] : make_int2(0, 0);
        int2 eD1 = (8 + sub < cn.w) ? cpD[8 + sub] : make_int2(0, 0);
        int2 eD2 = (16 + sub < cn.w) ? cpD[16 + sub] : make_int2(0, 0);
        const bf16* hf = hin + fl * 8;
        bf16x8 vA0 = *(const bf16x8*)(hf + (size_t)eA0.x * 64);
        bf16x8 vA1 = *(const bf16x8*)(hf + (size_t)eA1.x * 64);
        bf16x8 vA2 = *(const bf16x8*)(hf + (size_t)eA2.x * 64);
        bf16x8 vB0 = *(const bf16x8*)(hf + (size_t)eB0.x * 64);
        bf16x8 vB1 = *(const bf16x8*)(hf + (size_t)eB1.x * 64);
        bf16x8 vB2 = *(const bf16x8*)(hf + (size_t)eB2.x * 64);
        bf16x8 vC0 = *(const bf16x8*)(hf + (size_t)eC0.x * 64);
        bf16x8 vC1 = *(const bf16x8*)(hf + (size_t)eC1.x * 64);
        bf16x8 vC2 = *(const bf16x8*)(hf + (size_t)eC2.x * 64);
        bf16x8 vD0 = *(const bf16x8*)(hf + (size_t)eD0.x * 64);
        bf16x8 vD1 = *(const bf16x8*)(hf + (size_t)eD1.x * 64);
        bf16x8 vD2 = *(const bf16x8*)(hf + (size_t)eD2.x * 64);
        float wA0 = __int_as_float(eA0.y), wA1 = __int_as_float(eA1.y), wA2 = __int_as_float(eA2.y);
        float wB0 = __int_as_float(eB0.y), wB1 = __int_as_float(eB1.y), wB2 = __int_as_float(eB2.y);
        float wC0 = __int_as_float(eC0.y), wC1 = __int_as_float(eC1.y), wC2 = __int_as_float(eC2.y);
        float wD0 = __int_as_float(eD0.y), wD1 = __int_as_float(eD1.y), wD2 = __int_as_float(eD2.y);
        #pragma unroll
        for (int i = 0; i < 8; i++) {
            a[i] = wA0 * b2f_bits(vA0[i]) + wA1 * b2f_bits(vA1[i]) + wA2 * b2f_bits(vA2[i]);
            c[i] = wB0 * b2f_bits(vB0[i]) + wB1 * b2f_bits(vB1[i]) + wB2 * b2f_bits(vB2[i]);
            d[i] = wC0 * b2f_bits(vC0[i]) + wC1 * b2f_bits(vC1[i]) + wC2 * b2f_bits(vC2[i]);
            g[i] = wD0 * b2f_bits(vD0[i]) + wD1 * b2f_bits(vD1[i]) + wD2 * b2f_bits(vD2[i]);
        }
    } else {
        row_accum_gen<false>(hin, cpA, cn.x, dis, sub, fl, a);
        row_accum_gen<false>(hin, cpB, cn.y, dis, sub, fl, c);
        row_accum_gen<false>(hin, cpC, cn.z, dis, sub, fl, d);
        row_accum_gen<false>(hin, cpD, cn.w, dis, sub, fl, g);
    }

    #pragma unroll
    for (int i = 0; i < 8; i++) {
        a[i] += __shfl_xor(a[i], 8);  c[i] += __shfl_xor(c[i], 8);
        d[i] += __shfl_xor(d[i], 8);  g[i] += __shfl_xor(g[i], 8);
    }
    #pragma unroll
    for (int i = 0; i < 8; i++) {
        a[i] += __shfl_xor(a[i], 16); c[i] += __shfl_xor(c[i], 16);
        d[i] += __shfl_xor(d[i], 16); g[i] += __shfl_xor(g[i], 16);
    }
    #pragma unroll
    for (int i = 0; i < 8; i++) {
        a[i] += __shfl_xor(a[i], 32); c[i] += __shfl_xor(c[i], 32);
        d[i] += __shfl_xor(d[i], 32); g[i] += __shfl_xor(g[i], 32);
    }

    if (sub == 0) {
        bf16x8 ovA, ovB, ovC, ovD;
        #pragma unroll
        for (int i = 0; i < 8; i++) {
            bf16 tA = f2b(a[i] * dr.x);
            bf16 tB = f2b(c[i] * dr.y);
            bf16 tC = f2b(d[i] * dr.z);
            bf16 tD = f2b(g[i] * dr.w);
            ovA[i] = *(short*)&tA;
            ovB[i] = *(short*)&tB;
            ovC[i] = *(short*)&tC;
            ovD[i] = *(short*)&tD;
        }
        *(bf16x8*)(hout + (size_t)(r0 + 0) * 64 + fl * 8) = ovA;
        *(bf16x8*)(hout + (size_t)(r0 + 1) * 64 + fl * 8) = ovB;
        *(bf16x8*)(hout + (size_t)(r0 + 2) * 64 + fl * 8) = ovC;
        *(bf16x8*)(hout + (size_t)(r0 + 3) * 64 + fl * 8) = ovD;
    }
}

// ---------------- persistent-wave GEMM: out = H[NN x 256] @ Wcat[256 x 64] + bias ----
// R15: 1024 persistent waves; B register-resident; double-buffered A prefetch.
// R17: A-load adapted to plane layout: k = ks*32+q*8+i -> plane ks>>1, feat (ks&1)*32+q*8
#define GWAVES 1024
#define NT (NN / 16)   // 6250 row-tiles

__global__ __launch_bounds__(256, 1) void gemm_kernel(const bf16* __restrict__ H,
                                                      const bf16* __restrict__ Wt,
                                                      const float* __restrict__ bias,
                                                      float* __restrict__ outb) {
    int wave = threadIdx.x >> 6;
    int lane = threadIdx.x & 63;
    int m = lane & 15, q = lane >> 4;
    int w = blockIdx.x * 4 + wave;

    // B register-resident: all 4 col-tiles x 8 k-slices
    bf16x8 B[4][8];
    #pragma unroll
    for (int n = 0; n < 4; n++) {
        const bf16* brow = Wt + (size_t)(n * 16 + m) * 256 + q * 8;
        #pragma unroll
        for (int ks = 0; ks < 8; ks++) B[n][ks] = *(const bf16x8*)(brow + ks * 32);
    }
    float bv[4];
    #pragma unroll
    for (int n = 0; n < 4; n++) bv[n] = bias[n * 16 + m];

    if (w >= NT) return;

    bf16x8 A0[8], A1[8];

    #define LOADA(dst_, t_)                                                      \
        {                                                                        \
            _Pragma("unroll")                                                    \
            for (int ks = 0; ks < 8; ks++)                                       \
                dst_[ks] = *(const bf16x8*)(H +                                  \
                    ((size_t)(ks >> 1) * NN + (size_t)((t_)*16 + m)) * 64 +      \
                    (ks & 1) * 32 + q * 8);                                      \
        }

    #define COMP(src_, t_)                                                   \
        {                                                                    \
            _Pragma("unroll")                                                \
            for (int n = 0; n < 4; n++) {                                    \
                f32x4 acc = {0.f, 0.f, 0.f, 0.f};                            \
                _Pragma("unroll")                                            \
                for (int ks = 0; ks < 8; ks++)                               \
                    acc = __builtin_amdgcn_mfma_f32_16x16x32_bf16(           \
                        src_[ks], B[n][ks], acc, 0, 0, 0);                   \
                _Pragma("unroll")                                            \
                for (int r = 0; r < 4; r++)                                  \
                    outb[(size_t)((t_)*16 + q * 4 + r) * 64 + n * 16 + m] =  \
                        acc[r] + bv[n];                                      \
            }                                                                \
        }

    int t = w;
    LOADA(A0, t)
    while (true) {
        int t1 = t + GWAVES;
        if (t1 < NT) LOADA(A1, t1)
        COMP(A0, t)
        if (t1 >= NT) return;
        int t2 = t1 + GWAVES;
        if (t2 < NT) LOADA(A0, t2)
        COMP(A1, t1)
        if (t2 >= NT) return;
        t = t2;
    }
    #undef LOADA
    #undef COMP
}

// ---------------- GraphNorm: single-pass sum+sumsq ----------------
#define CH 32
#define STAT_WAVES ((NN + CH - 1) / CH)
#define STAT_BLOCKS ((STAT_WAVES * 64 + 255) / 256)

__global__ __launch_bounds__(256) void stats_kernel(const float* __restrict__ outb,
                                                    const int* __restrict__ batch,
                                                    float* __restrict__ gsum,
                                                    float* __restrict__ gssq,
                                                    float* __restrict__ gcnt) {
    int wid = (blockIdx.x * 256 + threadIdx.x) >> 6;
    int lane = threadIdx.x & 63;
    int n0 = wid * CH;
    if (n0 >= NN) return;
    int n1 = min(n0 + CH, NN);
    int g0 = batch[n0];
    if (n1 == n0 + CH && batch[n1 - 1] == g0) {
        float s = 0.f, s2 = 0.f;
        #pragma unroll
        for (int i = 0; i < CH; i++) {
            float v = outb[(size_t)(n0 + i) * 64 + lane];
            s += v; s2 += v * v;
        }
        atomicAdd(&gsum[g0 * 64 + lane], s);
        atomicAdd(&gssq[g0 * 64 + lane], s2);
        if (lane == 0) atomicAdd(&gcnt[g0], (float)CH);
    } else {
        int cur = g0; float s = 0.f, s2 = 0.f; int cl = 0;
        for (int i = n0; i < n1; i++) {
            int g = batch[i];
            if (g != cur) {
                atomicAdd(&gsum[cur * 64 + lane], s);
                atomicAdd(&gssq[cur * 64 + lane], s2);
                if (lane == 0) atomicAdd(&gcnt[cur], (float)cl);
                s = 0.f; s2 = 0.f; cl = 0; cur = g;
            }
            float v = outb[(size_t)i * 64 + lane];
            s += v; s2 += v * v; cl++;
        }
        atomicAdd(&gsum[cur * 64 + lane], s);
        atomicAdd(&gssq[cur * 64 + lane], s2);
        if (lane == 0) atomicAdd(&gcnt[cur], (float)cl);
    }
}

// mm/rstd from raw stats: mm = mean*ms; var = E[v^2]-2*mm*E[v]+mm^2
__device__ __forceinline__ void graph_mr(const float* gsum, const float* gssq,
                                         const float* gcnt, int g, int lane, float ms,
                                         float& mm, float& r) {
    float c = fmaxf(gcnt[g], 1.f);
    float mean = gsum[g * 64 + lane] / c;
    float msq = gssq[g * 64 + lane] / c;
    mm = mean * ms;
    float var = fmaxf(msq - 2.f * mm * mean + mm * mm, 0.f);
    r = rsqrtf(var + EPSV);
}

// normalize + residual + relu + write h_emb + pool accumulation
__global__ __launch_bounds__(256) void final_kernel(const float* __restrict__ outb,
                                                    const int* __restrict__ batch,
                                                    const float* __restrict__ xg,
                                                    const float* __restrict__ gsum,
                                                    const float* __restrict__ gssq,
                                                    const float* __restrict__ gcnt,
                                                    const float* __restrict__ gw_,
                                                    const float* __restrict__ gb_,
                                                    const float* __restrict__ ms_,
                                                    float* __restrict__ psum,
                                                    int* __restrict__ pmax,
                                                    float* __restrict__ hemb) {
    int wid = (blockIdx.x * 256 + threadIdx.x) >> 6;
    int lane = threadIdx.x & 63;
    int n0 = wid * CH;
    if (n0 >= NN) return;
    int n1 = min(n0 + CH, NN);
    float gw = gw_[lane], gb = gb_[lane], ms = ms_[lane];
    int g0 = batch[n0];
    if (n1 == n0 + CH && batch[n1 - 1] == g0) {
        float m, r;
        graph_mr(gsum, gssq, gcnt, g0, lane, ms, m, r);
        float ps = 0.f, pm = 0.f;
        #pragma unroll
        for (int i = 0; i < CH; i++) {
            size_t idx = (size_t)(n0 + i) * 64 + lane;
            float hn = gw * (outb[idx] - m) * r + gb;
            float he = hn + xg[idx];
            he = he > 0.f ? he : 0.f;
            hemb[idx] = he;
            ps += he;
            pm = fmaxf(pm, he);
        }
        atomicAdd(&psum[g0 * 64 + lane], ps);
        atomicMax(&pmax[g0 * 64 + lane], __float_as_int(pm));
    } else {
        int cur = g0;
        float m, r;
        graph_mr(gsum, gssq, gcnt, cur, lane, ms, m, r);
        float ps = 0.f, pm = 0.f;
        for (int i = n0; i < n1; i++) {
            int g = batch[i];
            if (g != cur) {
                atomicAdd(&psum[cur * 64 + lane], ps);
                atomicMax(&pmax[cur * 64 + lane], __float_as_int(pm));
                ps = 0.f; pm = 0.f; cur = g;
                graph_mr(gsum, gssq, gcnt, cur, lane, ms, m, r);
            }
            size_t idx = (size_t)i * 64 + lane;
            float hn = gw * (outb[idx] - m) * r + gb;
            float he = hn + xg[idx];
            he = he > 0.f ? he : 0.f;
            hemb[idx] = he;
            ps += he;
            pm = fmaxf(pm, he);
        }
        atomicAdd(&psum[cur * 64 + lane], ps);
        atomicMax(&pmax[cur * 64 + lane], __float_as_int(pm));
    }
}

__global__ __launch_bounds__(256) void pool_kernel(const float* __restrict__ psum,
                                                   const int* __restrict__ pmax,
                                                   const float* __restrict__ gcnt,
                                                   float* __restrict__ flat) {
    int i = blockIdx.x * 256 + threadIdx.x;
    if (i >= NG * FD) return;
    int g = i >> 6, f = i & 63;
    float c = fmaxf(gcnt[g], 1.f);
    flat[(size_t)g * 128 + f] = psum[i] / c;
    flat[(size_t)g * 128 + 64 + f] = __int_as_float(pmax[i]);
}

// ---------------- launch ----------------
extern "C" void kernel_launch(void* const* d_in, const int* in_sizes, int n_in,
                              void* d_out, int out_size, void* d_ws, size_t ws_size,
                              hipStream_t stream) {
    const float* x = (const float*)d_in[0];
    const int* ei = (const int*)d_in[1];
    const int* batch = (const int*)d_in[2];
    const float* ew = (const float*)d_in[3];
    const float* W = (const float*)d_in[4];   // [4,64,64]
    const float* bias = (const float*)d_in[5];
    const float* gnw = (const float*)d_in[6];
    const float* gnb = (const float*)d_in[7];
    const float* gms = (const float*)d_in[8];

    const int* src = ei;
    const int* dst = ei + NE;

    char* ws = (char*)d_ws;
    float* gsum = (float*)(ws + OFF_GSUM);
    float* gssq = (float*)(ws + OFF_GSSQ);
    float* gcnt = (float*)(ws + OFF_GCNT);
    float* psum = (float*)(ws + OFF_PSUM);
    int* pmax = (int*)(ws + OFF_PMAX);
    int* cnts = (int*)(ws + OFF_CNT);
    float* dis = (float*)(ws + OFF_DIS);
    int* rowp = (int*)(ws + OFF_ROWP);
    int* bsum = (int*)(ws + OFF_BSUM);
    bf16* Wt = (bf16*)(ws + OFF_WT);
    int2* csr = (int2*)(ws + OFF_CSR);
    bf16* H = (bf16*)(ws + OFF_H);           // plane k at H + k*NN*64
    float* outb = (float*)(ws + OFF_OUT);
    int2* csrt = (int2*)(ws + OFF_CSRT);
    int* cc = (int*)(ws + OFF_CC);

    float* hemb = (float*)d_out;
    float* flat = hemb + (size_t)NN * FD;

    hipMemsetAsync(d_ws, 0, ZERO_BYTES, stream);

    const size_t PL = (size_t)NN * 64;   // plane stride (bf16 elems)
    const int HOPB = (NN / 2 + 3) / 4;   // 2 rows/wave, 4 waves/block
    const int HOPB4 = (NN / 4 + 3) / 4;  // 4 rows/wave, 4 waves/block
    const int GFB = (NG * FD + 255) / 256;
    const int ADDB = (CCN + 255) / 256;

    coarse_fused_kernel<<<CB + XCB + 64, 256, 0, stream>>>(dst, cc, x, H, W, Wt);
    scan_blocks<<<SCB2, 256, 0, stream>>>(cc, bsum, CCN);
    bsum_scan<<<1, 256, 0, stream>>>(bsum, SCB2);
    scan_add2<<<ADDB, 256, 0, stream>>>(cc, bsum, CCN);
    scatter2_kernel<<<CB, 256, 0, stream>>>(src, dst, ew, cc, csrt);
    fine_kernel<<<NB1, 256, 0, stream>>>(cc, csrt, csr, rowp, cnts, dis);

    hop_kernel<true><<<HOPB, 256, 0, stream>>>(H, H + PL, rowp, cnts, csr, dis);              // h1 (+rescale)
    hop4_kernel<<<HOPB4, 256, 0, stream>>>(H + PL, H + 2 * PL, rowp, cnts, csr, dis);         // h2
    hop4_kernel<<<HOPB4, 256, 0, stream>>>(H + 2 * PL, H + 3 * PL, rowp, cnts, csr, dis);     // h3

    gemm_kernel<<<GWAVES / 4, 256, 0, stream>>>(H, Wt, bias, outb);

    stats_kernel<<<STAT_BLOCKS, 256, 0, stream>>>(outb, batch, gsum, gssq, gcnt);
    final_kernel<<<STAT_BLOCKS, 256, 0, stream>>>(outb, batch, x, gsum, gssq, gcnt,
                                                  gnw, gnb, gms, psum, pmax, hemb);
    pool_kernel<<<GFB, 256, 0, stream>>>(psum, pmax, gcnt, flat);
}

// Round 9
// 339.846 us; speedup vs baseline: 1.0329x; 1.0329x over previous
//
#include <hip/hip_runtime.h>
#include <hip/hip_bf16.h>

// Problem constants (fixed by the reference)
#define NN 100000
#define NE 1600000
#define NG 64
#define FD 64
#define EPSV 1e-5f

typedef __hip_bfloat16 bf16;
typedef __attribute__((ext_vector_type(8))) short bf16x8;  // 8 bf16 = 4 VGPRs (MFMA A/B frag)
typedef __attribute__((ext_vector_type(4))) float f32x4;   // MFMA C/D frag

__device__ __forceinline__ float ldb(bf16 v) { return __bfloat162float(v); }
__device__ __forceinline__ bf16 f2b(float v) { return __float2bfloat16(v); }
__device__ __forceinline__ float b2f_bits(short s) {   // exact bf16 -> fp32
    return __uint_as_float(((unsigned)(unsigned short)s) << 16);
}

// ---------------- counting-sort CSR build parameters ----------------
// R13/R14: 2-level LDS counting sort. R15: persistent-wave register-resident GEMM.
// R16: hop row-pairs. R17: H planes (write fix); R=4 serialized at 44 VGPR. R18:
// 2-row on planes = hop optimum (42us, 28 VGPR). R19: launch_bounds(256,4) did NOT
// unlock hoisting (still 44 VGPR, 48us) -> R>=2 MLP path dead at HIP level; REVERTED.
// R20: hops back to 2-row; stats fused into gemm epilogue (kills 25.6MB pass +
// dispatch); bsum_scan/scan_add2 dispatches killed (readers compute the 120-entry
// bsum prefix inline in LDS).
#define NB1 391                      // coarse buckets (dst>>8), 100000/256 -> 0..390
#define CB 625                       // coarse blocks
#define EPB 2560                     // edges per coarse block (CB*EPB == NE exactly)
#define CCN (NB1 * CB)               // count-matrix entries = 244375
#define SCB2 ((CCN + 2047) / 2048)   // scan blocks over count matrix = 120

// bijective chunked XCD swizzle (m204 variant): consecutive logical blocks -> same XCD
__device__ __forceinline__ int xcd_chunk(int bid, int nwg) {
    int q = nwg >> 3, r = nwg & 7;
    int xcd = bid & 7, j = bid >> 3;
    return (xcd < r ? xcd * (q + 1) : r * (q + 1) + (xcd - r) * q) + j;
}

// ---------------- workspace layout (bytes) ----------------
constexpr size_t ALGN(size_t x) { return (x + 255) & ~(size_t)255; }
constexpr size_t OFF_GSUM = 0;                                         // float[NG*FD]
constexpr size_t OFF_GSSQ = OFF_GSUM + ALGN((size_t)NG * FD * 4);      // float[NG*FD]
constexpr size_t OFF_GCNT = OFF_GSSQ + ALGN((size_t)NG * FD * 4);      // float[NG]
constexpr size_t OFF_PSUM = OFF_GCNT + ALGN((size_t)NG * 4);           // float[NG*FD]
constexpr size_t OFF_PMAX = OFF_PSUM + ALGN((size_t)NG * FD * 4);      // int[NG*FD] (relu>=0 so 0-init ok)
constexpr size_t ZERO_BYTES = OFF_PMAX + ALGN((size_t)NG * FD * 4);    // everything above memset(0)
constexpr size_t OFF_CNT  = ZERO_BYTES;                                // int[NN] (written by fine)
constexpr size_t OFF_DIS  = OFF_CNT  + ALGN((size_t)NN * 4);           // float[NN]
constexpr size_t OFF_ROWP = OFF_DIS  + ALGN((size_t)NN * 4);           // int[NN]
constexpr size_t OFF_BSUM = OFF_ROWP + ALGN((size_t)NN * 4);           // int[256] scan block totals
constexpr size_t OFF_WT   = OFF_BSUM + ALGN(256 * 4);                  // bf16[64][256] W^T stacked
constexpr size_t OFF_CSR  = OFF_WT   + ALGN(16384 * 2);                // int2[NE] final {src, w-bits}
constexpr size_t OFF_H    = OFF_CSR  + ALGN((size_t)NE * 8);           // bf16[4][NN][64] planes x|h1|h2|h3
constexpr size_t OFF_OUT  = OFF_H    + ALGN((size_t)NN * 256 * 2);     // float[NN*FD]
// aliases inside the OUT region (all dead before gemm):
constexpr size_t OFF_CSRT = OFF_OUT;                                   // int2[NE] {src|fine<<17, w}
constexpr size_t OFF_CC   = OFF_CSRT + ALGN((size_t)NE * 8);           // int[NB1*CB] count/scan matrix
static_assert(OFF_CC + (size_t)CCN * 4 - OFF_OUT <= (size_t)NN * FD * 4, "alias overflow");

// ---------------- phase 1: coarse LDS histogram + xcopy/wt streaming ----------------
#define XCB 6250   // NN*64 f32 -> bf16, 4 elems/thread: 6.4M/1024
__global__ __launch_bounds__(256) void coarse_fused_kernel(const int* __restrict__ dst,
                                                           int* __restrict__ cc,
                                                           const float* __restrict__ x,
                                                           bf16* __restrict__ H,
                                                           const float* __restrict__ W,
                                                           bf16* __restrict__ Wt) {
    int b = blockIdx.x;
    if (b < CB) {
        __shared__ int hist[NB1];
        for (int i = threadIdx.x; i < NB1; i += 256) hist[i] = 0;
        __syncthreads();
        int e0 = b * EPB + threadIdx.x;
        #pragma unroll
        for (int i = 0; i < EPB / 256; i++)
            atomicAdd(&hist[dst[e0 + i * 256] >> 8], 1);   // LDS atomic, rare conflicts
        __syncthreads();
        for (int i = threadIdx.x; i < NB1; i += 256)
            cc[(size_t)i * CB + b] = hist[i];              // [bucket][block] matrix
    } else if (b < CB + XCB) {
        // x (f32) -> plane0 (bf16), fully linear stream, 4 elems/thread
        int i = (b - CB) * 256 + threadIdx.x;              // 0 .. NN*64/4-1 exact
        float4 xv = ((const float4*)x)[i];
        bf16 t0 = f2b(xv.x), t1 = f2b(xv.y), t2 = f2b(xv.z), t3 = f2b(xv.w);
        ushort4 o;
        o.x = *(unsigned short*)&t0; o.y = *(unsigned short*)&t1;
        o.z = *(unsigned short*)&t2; o.w = *(unsigned short*)&t3;
        ((ushort4*)H)[i] = o;
    } else {
        int i = (b - CB - XCB) * 256 + threadIdx.x;  // 0..16383
        int n = i & 63, kk = i >> 6;
        Wt[n * 256 + kk] = f2b(W[kk * 64 + n]);
    }
}

// ---------------- scan of the count matrix (block-local scans + block totals) -------
#define SCAN_BLK 256
#define SCAN_ITEMS 8   // 2048 elems per block
__global__ __launch_bounds__(SCAN_BLK) void scan_blocks(int* __restrict__ data,
                                                        int* __restrict__ bsum, int n) {
    __shared__ int lds[SCAN_BLK];
    int t = threadIdx.x, b = blockIdx.x;
    int base = b * SCAN_BLK * SCAN_ITEMS + t * SCAN_ITEMS;
    int v[SCAN_ITEMS];
    int s = 0;
    #pragma unroll
    for (int i = 0; i < SCAN_ITEMS; i++) {
        int idx = base + i;
        v[i] = (idx < n) ? data[idx] : 0;
        s += v[i];
    }
    lds[t] = s;
    __syncthreads();
    for (int off = 1; off < SCAN_BLK; off <<= 1) {
        int x = (t >= off) ? lds[t - off] : 0;
        __syncthreads();
        lds[t] += x;
        __syncthreads();
    }
    int excl = lds[t] - s;
    if (t == SCAN_BLK - 1) bsum[b] = lds[t];   // per-block TOTAL (readers prefix it)
    int run = excl;
    #pragma unroll
    for (int i = 0; i < SCAN_ITEMS; i++) {
        int idx = base + i;
        if (idx < n) data[idx] = run;          // in-place: own range only, reads done
        run += v[i];
    }
}

// ---------------- phase 3: LDS-sorted coarse scatter, coalesced write-out ------------
// R20: computes the 120-entry bsum prefix inline (folded into the sc scan loop).
__global__ __launch_bounds__(256) void scatter2_kernel(const int* __restrict__ src,
                                                       const int* __restrict__ dst,
                                                       const float* __restrict__ ew,
                                                       const int* __restrict__ cc,
                                                       const int* __restrict__ bsum,
                                                       int2* __restrict__ csrt) {
    __shared__ int sc[512];        // bucket counts -> inclusive prefix (padded to 512)
    __shared__ int bp[128];        // bsum inclusive prefix (SCB2=120 entries)
    __shared__ int gdel[NB1];      // global_start - local_start per bucket
    __shared__ int2 stage[EPB];    // block's edges in bucket order
    __shared__ int sdel[EPB];      // per-slot global delta
    int t = threadIdx.x;
    int L = xcd_chunk(blockIdx.x, CB);   // adjacent logical blocks -> same XCD

    sc[t] = 0; sc[t + 256] = 0;
    if (t < 128) bp[t] = (t < SCB2) ? bsum[t] : 0;
    __syncthreads();

    int br[EPB / 256], px[EPB / 256], pw[EPB / 256];
    #pragma unroll
    for (int i = 0; i < EPB / 256; i++) {
        int e = L * EPB + i * 256 + t;
        int d = dst[e];
        int bk = d >> 8;
        int rk = atomicAdd(&sc[bk], 1);            // local rank within (bucket, block)
        br[i] = bk | (rk << 9);                    // bk<512 (9b), rk<2560 (12b)
        px[i] = src[e] | ((d & 255) << 17);        // src<2^17, fine dst bits 17..24
        pw[i] = __float_as_int(ew[e]);
    }
    __syncthreads();

    // inclusive scan of sc[0..511] (+ bp[0..127] folded in), Hillis-Steele
    for (int off = 1; off < 512; off <<= 1) {
        int a0 = (t >= off) ? sc[t - off] : 0;
        int a1 = sc[t + 256 - off];                // t+256 >= 256 >= off always
        int a2 = (off < 128 && t < 128 && t >= off) ? bp[t - off] : 0;
        __syncthreads();
        sc[t] += a0; sc[t + 256] += a1;
        if (off < 128 && t < 128) bp[t] += a2;
        __syncthreads();
    }

    for (int i = t; i < NB1; i += 256) {
        int idx = i * CB + L;
        int k = idx >> 11;
        int gpref = (k > 0) ? bp[k - 1] : 0;
        gdel[i] = cc[idx] + gpref - ((i > 0) ? sc[i - 1] : 0);
    }
    __syncthreads();

    #pragma unroll
    for (int i = 0; i < EPB / 256; i++) {
        int bk = br[i] & 511;
        int rk = br[i] >> 9;
        int slot = ((bk > 0) ? sc[bk - 1] : 0) + rk;
        stage[slot] = make_int2(px[i], pw[i]);
        sdel[slot] = gdel[bk];
    }
    __syncthreads();

    for (int j = t; j < EPB; j += 256)             // coalesced runs out
        csrt[(size_t)(sdel[j] + j)] = stage[j];
}

// ---------------- phase 4: per-bucket fine sort + rowp/cnts/dis emission ------------
// R20: computes bucket bounds from raw cc + inline bsum prefix.
__global__ __launch_bounds__(256) void fine_kernel(const int* __restrict__ cc,
                                                   const int* __restrict__ bsum,
                                                   const int2* __restrict__ csrt,
                                                   int2* __restrict__ csr,
                                                   int* __restrict__ rowp,
                                                   int* __restrict__ cnts,
                                                   float* __restrict__ dis) {
    __shared__ int hist[256];
    __shared__ float degw[256];
    __shared__ int pref[256];
    __shared__ int fcur[256];
    __shared__ int bp[128];
    __shared__ int bounds[2];
    int b = blockIdx.x;
    int t = threadIdx.x;
    hist[t] = 0; degw[t] = 0.f;
    if (t < 128) bp[t] = (t < SCB2) ? bsum[t] : 0;
    __syncthreads();
    for (int off = 1; off < 128; off <<= 1) {
        int x = (t < 128 && t >= off) ? bp[t - off] : 0;
        __syncthreads();
        if (t < 128) bp[t] += x;
        __syncthreads();
    }
    if (t == 0) {
        int i0 = b * CB, k0 = i0 >> 11;
        bounds[0] = cc[i0] + ((k0 > 0) ? bp[k0 - 1] : 0);
        if (b == NB1 - 1) bounds[1] = NE;
        else {
            int i1 = (b + 1) * CB, k1 = i1 >> 11;
            bounds[1] = cc[i1] + ((k1 > 0) ? bp[k1 - 1] : 0);
        }
    }
    __syncthreads();
    int base = bounds[0];
    int cnt = bounds[1] - base;

    for (int j = t; j < cnt; j += 256) {
        int2 e = csrt[base + j];
        int f = e.x >> 17;
        atomicAdd(&hist[f], 1);
        atomicAdd(&degw[f], __int_as_float(e.y));  // deg = sum of raw w per dst row
    }
    __syncthreads();
    int hv = hist[t];
    pref[t] = hv;
    __syncthreads();
    for (int off = 1; off < 256; off <<= 1) {
        int x = (t >= off) ? pref[t - off] : 0;
        __syncthreads();
        pref[t] += x;
        __syncthreads();
    }
    int ex = pref[t] - hv;                  // exclusive fine prefix
    fcur[t] = ex;
    int node = b * 256 + t;
    if (node < NN) {
        rowp[node] = base + ex;
        cnts[node] = hv;
        float s = degw[t];
        dis[node] = (s > 0.f) ? rsqrtf(s) : 0.f;
    }
    __syncthreads();
    for (int j = t; j < cnt; j += 256) {    // 2nd read hits L2 (33KB slice)
        int2 e = csrt[base + j];
        int f = e.x >> 17;
        int pos = atomicAdd(&fcur[f], 1);   // LDS atomic
        csr[base + pos] = make_int2(e.x & 0x1FFFF, e.y);
    }
}

// ---------------- hop: wide-vector gather, 2 rows per wave, plane layout ------------
// hin/hout are planes [NN][64]. FIRST: csr.y holds RAW w -> gather dis[e.x],
// nr = w*dis[src], write back so hops 2/3 read pre-scaled.
template <bool FIRST>
__device__ __forceinline__ void row_accum_gen(const bf16* __restrict__ hin,
                                              int2* cp, int cnt,
                                              const float* __restrict__ dis,
                                              int sub, int fl, float a[8]) {
    if (cnt <= 24) {
        int2 e0 = (sub < cnt) ? cp[sub] : make_int2(0, 0);
        int2 e1 = (8 + sub < cnt) ? cp[8 + sub] : make_int2(0, 0);
        int2 e2 = (16 + sub < cnt) ? cp[16 + sub] : make_int2(0, 0);
        bf16x8 v0 = *(const bf16x8*)(hin + (size_t)e0.x * 64 + fl * 8);
        bf16x8 v1 = *(const bf16x8*)(hin + (size_t)e1.x * 64 + fl * 8);
        bf16x8 v2 = *(const bf16x8*)(hin + (size_t)e2.x * 64 + fl * 8);
        float w0 = __int_as_float(e0.y);
        float w1 = __int_as_float(e1.y);
        float w2 = __int_as_float(e2.y);
        if (FIRST) {
            w0 *= dis[e0.x]; w1 *= dis[e1.x]; w2 *= dis[e2.x];
            if (fl == 0) {
                if (sub < cnt)      cp[sub].y      = __float_as_int(w0);
                if (8 + sub < cnt)  cp[8 + sub].y  = __float_as_int(w1);
                if (16 + sub < cnt) cp[16 + sub].y = __float_as_int(w2);
            }
        }
        #pragma unroll
        for (int i = 0; i < 8; i++)
            a[i] += w0 * b2f_bits(v0[i]) + w1 * b2f_bits(v1[i]) + w2 * b2f_bits(v2[i]);
    } else {
        float b[8] = {0, 0, 0, 0, 0, 0, 0, 0};
        int j = 0;
        for (; j + 16 <= cnt; j += 16) {
            int2 e0 = cp[j + sub];
            int2 e1 = cp[j + 8 + sub];
            bf16x8 v0 = *(const bf16x8*)(hin + (size_t)e0.x * 64 + fl * 8);
            bf16x8 v1 = *(const bf16x8*)(hin + (size_t)e1.x * 64 + fl * 8);
            float w0 = __int_as_float(e0.y);
            float w1 = __int_as_float(e1.y);
            if (FIRST) {
                w0 *= dis[e0.x]; w1 *= dis[e1.x];
                if (fl == 0) {
                    cp[j + sub].y     = __float_as_int(w0);
                    cp[j + 8 + sub].y = __float_as_int(w1);
                }
            }
            #pragma unroll
            for (int i = 0; i < 8; i++) a[i] += w0 * b2f_bits(v0[i]);
            #pragma unroll
            for (int i = 0; i < 8; i++) b[i] += w1 * b2f_bits(v1[i]);
        }
        for (; j < cnt; j += 8) {
            int jj = j + sub;
            int2 e = (jj < cnt) ? cp[jj] : make_int2(0, 0);
            bf16x8 v = *(const bf16x8*)(hin + (size_t)e.x * 64 + fl * 8);
            float w = __int_as_float(e.y);
            if (FIRST) {
                w *= dis[e.x];
                if (fl == 0 && jj < cnt) cp[jj].y = __float_as_int(w);
            }
            #pragma unroll
            for (int i = 0; i < 8; i++) a[i] += w * b2f_bits(v[i]);
        }
        #pragma unroll
        for (int i = 0; i < 8; i++) a[i] += b[i];
    }
}

// 2-row hop (proven 28-VGPR structure; R19's 4-row variant refused to hoist -> dead)
template <bool FIRST>
__global__ __launch_bounds__(256) void hop_kernel(const bf16* __restrict__ hin,  // plane k-1
                                                  bf16* __restrict__ hout,       // plane k
                                                  const int* __restrict__ rowp,
                                                  const int* __restrict__ cnts,
                                                  int2* __restrict__ csr,
                                                  const float* __restrict__ dis) {
    int pair = blockIdx.x * 4 + (threadIdx.x >> 6);
    int rowA = pair * 2;
    if (rowA >= NN) return;
    rowA = __builtin_amdgcn_readfirstlane(rowA);
    int rowB = rowA + 1;                     // NN even -> always valid
    int lane = threadIdx.x & 63;
    int sub = lane >> 3;   // edge slot 0..7
    int fl = lane & 7;     // feature octet 0..7

    int stA = rowp[rowA], cnA = cnts[rowA];
    int stB = rowp[rowB], cnB = cnts[rowB];
    float drA = dis[rowA], drB = dis[rowB];
    int2* cpA = csr + stA;
    int2* cpB = csr + stB;

    float a[8] = {0, 0, 0, 0, 0, 0, 0, 0};
    float c[8] = {0, 0, 0, 0, 0, 0, 0, 0};

    if (cnA <= 24 && cnB <= 24) {
        int2 eA0 = (sub < cnA) ? cpA[sub] : make_int2(0, 0);
        int2 eA1 = (8 + sub < cnA) ? cpA[8 + sub] : make_int2(0, 0);
        int2 eA2 = (16 + sub < cnA) ? cpA[16 + sub] : make_int2(0, 0);
        int2 eB0 = (sub < cnB) ? cpB[sub] : make_int2(0, 0);
        int2 eB1 = (8 + sub < cnB) ? cpB[8 + sub] : make_int2(0, 0);
        int2 eB2 = (16 + sub < cnB) ? cpB[16 + sub] : make_int2(0, 0);
        const bf16* hf = hin + fl * 8;
        bf16x8 vA0 = *(const bf16x8*)(hf + (size_t)eA0.x * 64);
        bf16x8 vA1 = *(const bf16x8*)(hf + (size_t)eA1.x * 64);
        bf16x8 vA2 = *(const bf16x8*)(hf + (size_t)eA2.x * 64);
        bf16x8 vB0 = *(const bf16x8*)(hf + (size_t)eB0.x * 64);
        bf16x8 vB1 = *(const bf16x8*)(hf + (size_t)eB1.x * 64);
        bf16x8 vB2 = *(const bf16x8*)(hf + (size_t)eB2.x * 64);
        float wA0 = __int_as_float(eA0.y);
        float wA1 = __int_as_float(eA1.y);
        float wA2 = __int_as_float(eA2.y);
        float wB0 = __int_as_float(eB0.y);
        float wB1 = __int_as_float(eB1.y);
        float wB2 = __int_as_float(eB2.y);
        if (FIRST) {
            wA0 *= dis[eA0.x]; wA1 *= dis[eA1.x]; wA2 *= dis[eA2.x];
            wB0 *= dis[eB0.x]; wB1 *= dis[eB1.x]; wB2 *= dis[eB2.x];
            if (fl == 0) {
                if (sub < cnA)      cpA[sub].y      = __float_as_int(wA0);
                if (8 + sub < cnA)  cpA[8 + sub].y  = __float_as_int(wA1);
                if (16 + sub < cnA) cpA[16 + sub].y = __float_as_int(wA2);
                if (sub < cnB)      cpB[sub].y      = __float_as_int(wB0);
                if (8 + sub < cnB)  cpB[8 + sub].y  = __float_as_int(wB1);
                if (16 + sub < cnB) cpB[16 + sub].y = __float_as_int(wB2);
            }
        }
        #pragma unroll
        for (int i = 0; i < 8; i++) {
            a[i] = wA0 * b2f_bits(vA0[i]) + wA1 * b2f_bits(vA1[i]) + wA2 * b2f_bits(vA2[i]);
            c[i] = wB0 * b2f_bits(vB0[i]) + wB1 * b2f_bits(vB1[i]) + wB2 * b2f_bits(vB2[i]);
        }
    } else {
        row_accum_gen<FIRST>(hin, cpA, cnA, dis, sub, fl, a);
        row_accum_gen<FIRST>(hin, cpB, cnB, dis, sub, fl, c);
    }

    #pragma unroll
    for (int i = 0; i < 8; i++) { a[i] += __shfl_xor(a[i], 8);  c[i] += __shfl_xor(c[i], 8); }
    #pragma unroll
    for (int i = 0; i < 8; i++) { a[i] += __shfl_xor(a[i], 16); c[i] += __shfl_xor(c[i], 16); }
    #pragma unroll
    for (int i = 0; i < 8; i++) { a[i] += __shfl_xor(a[i], 32); c[i] += __shfl_xor(c[i], 32); }

    if (sub == 0) {
        bf16x8 ovA, ovB;
        #pragma unroll
        for (int i = 0; i < 8; i++) {
            bf16 tA = f2b(a[i] * drA);
            bf16 tB = f2b(c[i] * drB);
            ovA[i] = *(short*)&tA;
            ovB[i] = *(short*)&tB;
        }
        *(bf16x8*)(hout + (size_t)rowA * 64 + fl * 8) = ovA;
        *(bf16x8*)(hout + (size_t)rowB * 64 + fl * 8) = ovB;
    }
}

// ---------------- persistent-wave GEMM + fused GraphNorm stats ----------------
// R15: 1024 persistent waves; B register-resident; double-buffered A prefetch.
// R17: plane-layout A-load. R20: stats (gsum/gssq/gcnt) fused into the epilogue:
// per tile, reduce sum/sumsq over rows in-register (Sigma_r then shfl over q) ->
// 128 atomics/tile to 64-consecutive addresses; batch-sorted fast path covers
// ~99% of tiles (63 graph boundaries / 6250 tiles).
#define GWAVES 1024
#define NT (NN / 16)   // 6250 row-tiles

__global__ __launch_bounds__(256, 1) void gemm_kernel(const bf16* __restrict__ H,
                                                      const bf16* __restrict__ Wt,
                                                      const float* __restrict__ bias,
                                                      const int* __restrict__ batch,
                                                      float* __restrict__ gsum,
                                                      float* __restrict__ gssq,
                                                      float* __restrict__ gcnt,
                                                      float* __restrict__ outb) {
    int wave = threadIdx.x >> 6;
    int lane = threadIdx.x & 63;
    int m = lane & 15, q = lane >> 4;
    int w = blockIdx.x * 4 + wave;

    // B register-resident: all 4 col-tiles x 8 k-slices
    bf16x8 B[4][8];
    #pragma unroll
    for (int n = 0; n < 4; n++) {
        const bf16* brow = Wt + (size_t)(n * 16 + m) * 256 + q * 8;
        #pragma unroll
        for (int ks = 0; ks < 8; ks++) B[n][ks] = *(const bf16x8*)(brow + ks * 32);
    }
    float bv[4];
    #pragma unroll
    for (int n = 0; n < 4; n++) bv[n] = bias[n * 16 + m];

    if (w >= NT) return;

    bf16x8 A0[8], A1[8];

    #define LOADA(dst_, t_)                                                      \
        {                                                                        \
            _Pragma("unroll")                                                    \
            for (int ks = 0; ks < 8; ks++)                                       \
                dst_[ks] = *(const bf16x8*)(H +                                  \
                    ((size_t)(ks >> 1) * NN + (size_t)((t_)*16 + m)) * 64 +      \
                    (ks & 1) * 32 + q * 8);                                      \
        }

    #define COMP(src_, t_)                                                          \
        {                                                                           \
            float s_[4], s2_[4], vals_[4][4];                                       \
            _Pragma("unroll")                                                       \
            for (int n = 0; n < 4; n++) {                                           \
                f32x4 acc = {0.f, 0.f, 0.f, 0.f};                                   \
                _Pragma("unroll")                                                   \
                for (int ks = 0; ks < 8; ks++)                                      \
                    acc = __builtin_amdgcn_mfma_f32_16x16x32_bf16(                  \
                        src_[ks], B[n][ks], acc, 0, 0, 0);                          \
                float ss = 0.f, ss2 = 0.f;                                          \
                _Pragma("unroll")                                                   \
                for (int r = 0; r < 4; r++) {                                       \
                    float val = acc[r] + bv[n];                                     \
                    vals_[n][r] = val;                                              \
                    outb[(size_t)((t_)*16 + q * 4 + r) * 64 + n * 16 + m] = val;    \
                    ss += val; ss2 += val * val;                                    \
                }                                                                   \
                s_[n] = ss; s2_[n] = ss2;                                           \
            }                                                                       \
            int gLo = batch[(t_)*16];                                               \
            int gHi = batch[(t_)*16 + 15];                                          \
            if (gLo == gHi) {                                                       \
                _Pragma("unroll")                                                   \
                for (int n = 0; n < 4; n++) {                                       \
                    s_[n] += __shfl_xor(s_[n], 16);  s_[n] += __shfl_xor(s_[n], 32);   \
                    s2_[n] += __shfl_xor(s2_[n], 16); s2_[n] += __shfl_xor(s2_[n], 32);\
                }                                                                   \
                if (q == 0) {                                                       \
                    _Pragma("unroll")                                               \
                    for (int n = 0; n < 4; n++) {                                   \
                        atomicAdd(&gsum[gLo * 64 + n * 16 + m], s_[n]);             \
                        atomicAdd(&gssq[gLo * 64 + n * 16 + m], s2_[n]);            \
                    }                                                               \
                }                                                                   \
                if (lane == 0) atomicAdd(&gcnt[gLo], 16.f);                         \
            } else {                                                               \
                int4 b4 = *(const int4*)(batch + (t_)*16 + q * 4);                  \
                int gr_[4] = {b4.x, b4.y, b4.z, b4.w};                              \
                _Pragma("unroll")                                                   \
                for (int r = 0; r < 4; r++) {                                       \
                    _Pragma("unroll")                                               \
                    for (int n = 0; n < 4; n++) {                                   \
                        atomicAdd(&gsum[gr_[r] * 64 + n * 16 + m], vals_[n][r]);    \
                        atomicAdd(&gssq[gr_[r] * 64 + n * 16 + m],                  \
                                  vals_[n][r] * vals_[n][r]);                       \
                    }                                                               \
                }                                                                   \
                if (lane < 16) atomicAdd(&gcnt[batch[(t_)*16 + lane]], 1.f);        \
            }                                                                       \
        }

    int t = w;
    LOADA(A0, t)
    while (true) {
        int t1 = t + GWAVES;
        if (t1 < NT) LOADA(A1, t1)
        COMP(A0, t)
        if (t1 >= NT) return;
        int t2 = t1 + GWAVES;
        if (t2 < NT) LOADA(A0, t2)
        COMP(A1, t1)
        if (t2 >= NT) return;
        t = t2;
    }
    #undef LOADA
    #undef COMP
}

// ---------------- GraphNorm finish ----------------
#define CH 32
#define STAT_WAVES ((NN + CH - 1) / CH)
#define STAT_BLOCKS ((STAT_WAVES * 64 + 255) / 256)

// mm/rstd from raw stats: mm = mean*ms; var = E[v^2]-2*mm*E[v]+mm^2
__device__ __forceinline__ void graph_mr(const float* gsum, const float* gssq,
                                         const float* gcnt, int g, int lane, float ms,
                                         float& mm, float& r) {
    float c = fmaxf(gcnt[g], 1.f);
    float mean = gsum[g * 64 + lane] / c;
    float msq = gssq[g * 64 + lane] / c;
    mm = mean * ms;
    float var = fmaxf(msq - 2.f * mm * mean + mm * mm, 0.f);
    r = rsqrtf(var + EPSV);
}

// normalize + residual + relu + write h_emb + pool accumulation
__global__ __launch_bounds__(256) void final_kernel(const float* __restrict__ outb,
                                                    const int* __restrict__ batch,
                                                    const float* __restrict__ xg,
                                                    const float* __restrict__ gsum,
                                                    const float* __restrict__ gssq,
                                                    const float* __restrict__ gcnt,
                                                    const float* __restrict__ gw_,
                                                    const float* __restrict__ gb_,
                                                    const float* __restrict__ ms_,
                                                    float* __restrict__ psum,
                                                    int* __restrict__ pmax,
                                                    float* __restrict__ hemb) {
    int wid = (blockIdx.x * 256 + threadIdx.x) >> 6;
    int lane = threadIdx.x & 63;
    int n0 = wid * CH;
    if (n0 >= NN) return;
    int n1 = min(n0 + CH, NN);
    float gw = gw_[lane], gb = gb_[lane], ms = ms_[lane];
    int g0 = batch[n0];
    if (n1 == n0 + CH && batch[n1 - 1] == g0) {
        float m, r;
        graph_mr(gsum, gssq, gcnt, g0, lane, ms, m, r);
        float ps = 0.f, pm = 0.f;
        #pragma unroll
        for (int i = 0; i < CH; i++) {
            size_t idx = (size_t)(n0 + i) * 64 + lane;
            float hn = gw * (outb[idx] - m) * r + gb;
            float he = hn + xg[idx];
            he = he > 0.f ? he : 0.f;
            hemb[idx] = he;
            ps += he;
            pm = fmaxf(pm, he);
        }
        atomicAdd(&psum[g0 * 64 + lane], ps);
        atomicMax(&pmax[g0 * 64 + lane], __float_as_int(pm));
    } else {
        int cur = g0;
        float m, r;
        graph_mr(gsum, gssq, gcnt, cur, lane, ms, m, r);
        float ps = 0.f, pm = 0.f;
        for (int i = n0; i < n1; i++) {
            int g = batch[i];
            if (g != cur) {
                atomicAdd(&psum[cur * 64 + lane], ps);
                atomicMax(&pmax[cur * 64 + lane], __float_as_int(pm));
                ps = 0.f; pm = 0.f; cur = g;
                graph_mr(gsum, gssq, gcnt, cur, lane, ms, m, r);
            }
            size_t idx = (size_t)i * 64 + lane;
            float hn = gw * (outb[idx] - m) * r + gb;
            float he = hn + xg[idx];
            he = he > 0.f ? he : 0.f;
            hemb[idx] = he;
            ps += he;
            pm = fmaxf(pm, he);
        }
        atomicAdd(&psum[cur * 64 + lane], ps);
        atomicMax(&pmax[cur * 64 + lane], __float_as_int(pm));
    }
}

__global__ __launch_bounds__(256) void pool_kernel(const float* __restrict__ psum,
                                                   const int* __restrict__ pmax,
                                                   const float* __restrict__ gcnt,
                                                   float* __restrict__ flat) {
    int i = blockIdx.x * 256 + threadIdx.x;
    if (i >= NG * FD) return;
    int g = i >> 6, f = i & 63;
    float c = fmaxf(gcnt[g], 1.f);
    flat[(size_t)g * 128 + f] = psum[i] / c;
    flat[(size_t)g * 128 + 64 + f] = __int_as_float(pmax[i]);
}

// ---------------- launch ----------------
extern "C" void kernel_launch(void* const* d_in, const int* in_sizes, int n_in,
                              void* d_out, int out_size, void* d_ws, size_t ws_size,
                              hipStream_t stream) {
    const float* x = (const float*)d_in[0];
    const int* ei = (const int*)d_in[1];
    const int* batch = (const int*)d_in[2];
    const float* ew = (const float*)d_in[3];
    const float* W = (const float*)d_in[4];   // [4,64,64]
    const float* bias = (const float*)d_in[5];
    const float* gnw = (const float*)d_in[6];
    const float* gnb = (const float*)d_in[7];
    const float* gms = (const float*)d_in[8];

    const int* src = ei;
    const int* dst = ei + NE;

    char* ws = (char*)d_ws;
    float* gsum = (float*)(ws + OFF_GSUM);
    float* gssq = (float*)(ws + OFF_GSSQ);
    float* gcnt = (float*)(ws + OFF_GCNT);
    float* psum = (float*)(ws + OFF_PSUM);
    int* pmax = (int*)(ws + OFF_PMAX);
    int* cnts = (int*)(ws + OFF_CNT);
    float* dis = (float*)(ws + OFF_DIS);
    int* rowp = (int*)(ws + OFF_ROWP);
    int* bsum = (int*)(ws + OFF_BSUM);
    bf16* Wt = (bf16*)(ws + OFF_WT);
    int2* csr = (int2*)(ws + OFF_CSR);
    bf16* H = (bf16*)(ws + OFF_H);           // plane k at H + k*NN*64
    float* outb = (float*)(ws + OFF_OUT);
    int2* csrt = (int2*)(ws + OFF_CSRT);
    int* cc = (int*)(ws + OFF_CC);

    float* hemb = (float*)d_out;
    float* flat = hemb + (size_t)NN * FD;

    hipMemsetAsync(d_ws, 0, ZERO_BYTES, stream);

    const size_t PL = (size_t)NN * 64;   // plane stride (bf16 elems)
    const int HOPB = (NN / 2 + 3) / 4;   // 2 rows/wave, 4 waves/block
    const int GFB = (NG * FD + 255) / 256;

    coarse_fused_kernel<<<CB + XCB + 64, 256, 0, stream>>>(dst, cc, x, H, W, Wt);
    scan_blocks<<<SCB2, 256, 0, stream>>>(cc, bsum, CCN);
    scatter2_kernel<<<CB, 256, 0, stream>>>(src, dst, ew, cc, bsum, csrt);
    fine_kernel<<<NB1, 256, 0, stream>>>(cc, bsum, csrt, csr, rowp, cnts, dis);

    hop_kernel<true><<<HOPB, 256, 0, stream>>>(H, H + PL, rowp, cnts, csr, dis);              // h1 (+rescale)
    hop_kernel<false><<<HOPB, 256, 0, stream>>>(H + PL, H + 2 * PL, rowp, cnts, csr, dis);    // h2
    hop_kernel<false><<<HOPB, 256, 0, stream>>>(H + 2 * PL, H + 3 * PL, rowp, cnts, csr, dis);// h3

    gemm_kernel<<<GWAVES / 4, 256, 0, stream>>>(H, Wt, bias, batch, gsum, gssq, gcnt, outb);

    final_kernel<<<STAT_BLOCKS, 256, 0, stream>>>(outb, batch, x, gsum, gssq, gcnt,
                                                  gnw, gnb, gms, psum, pmax, hemb);
    pool_kernel<<<GFB, 256, 0, stream>>>(psum, pmax, gcnt, flat);
}

// Round 10
// 326.415 us; speedup vs baseline: 1.0754x; 1.0411x over previous
//
#include <hip/hip_runtime.h>
#include <hip/hip_bf16.h>

// Problem constants (fixed by the reference)
#define NN 100000
#define NE 1600000
#define NG 64
#define FD 64
#define EPSV 1e-5f

typedef __hip_bfloat16 bf16;
typedef __attribute__((ext_vector_type(8))) short bf16x8;  // 8 bf16 = 4 VGPRs (MFMA A/B frag)
typedef __attribute__((ext_vector_type(4))) float f32x4;   // MFMA C/D frag

__device__ __forceinline__ float ldb(bf16 v) { return __bfloat162float(v); }
__device__ __forceinline__ bf16 f2b(float v) { return __float2bfloat16(v); }
__device__ __forceinline__ float b2f_bits(short s) {   // exact bf16 -> fp32
    return __uint_as_float(((unsigned)(unsigned short)s) << 16);
}

// ---------------- counting-sort CSR build parameters ----------------
// R13/R14: 2-level LDS counting sort. R15: persistent-wave register-resident GEMM.
// R16: hop row-pairs. R17: H planes (write fix); R=4 serialized at 44 VGPR. R18:
// 2-row on planes = hop optimum (42us, 28 VGPR). R19: launch_bounds(256,4) didn't
// unlock hoisting -> reverted. R20: scan-dispatch kills GOOD (kept); stats-fusion
// into gemm BAD (VGPR 132 < B-resident threshold -> B evicted, gemm 67us at 8.5%
// occupancy) -> R21 unfuses: exact R18 gemm + separate stats_kernel restored.
// Register-allocator lesson (R17/R19/R20): ~130 live VGPRs is the practical cap the
// compiler will hold across load-use regions; the persistent gemm only works when
// B[4][8]+A0/A1 fit WITHOUT extra epilogue state.
#define NB1 391                      // coarse buckets (dst>>8), 100000/256 -> 0..390
#define CB 625                       // coarse blocks
#define EPB 2560                     // edges per coarse block (CB*EPB == NE exactly)
#define CCN (NB1 * CB)               // count-matrix entries = 244375
#define SCB2 ((CCN + 2047) / 2048)   // scan blocks over count matrix = 120

// bijective chunked XCD swizzle (m204 variant): consecutive logical blocks -> same XCD
__device__ __forceinline__ int xcd_chunk(int bid, int nwg) {
    int q = nwg >> 3, r = nwg & 7;
    int xcd = bid & 7, j = bid >> 3;
    return (xcd < r ? xcd * (q + 1) : r * (q + 1) + (xcd - r) * q) + j;
}

// ---------------- workspace layout (bytes) ----------------
constexpr size_t ALGN(size_t x) { return (x + 255) & ~(size_t)255; }
constexpr size_t OFF_GSUM = 0;                                         // float[NG*FD]
constexpr size_t OFF_GSSQ = OFF_GSUM + ALGN((size_t)NG * FD * 4);      // float[NG*FD]
constexpr size_t OFF_GCNT = OFF_GSSQ + ALGN((size_t)NG * FD * 4);      // float[NG]
constexpr size_t OFF_PSUM = OFF_GCNT + ALGN((size_t)NG * 4);           // float[NG*FD]
constexpr size_t OFF_PMAX = OFF_PSUM + ALGN((size_t)NG * FD * 4);      // int[NG*FD] (relu>=0 so 0-init ok)
constexpr size_t ZERO_BYTES = OFF_PMAX + ALGN((size_t)NG * FD * 4);    // everything above memset(0)
constexpr size_t OFF_CNT  = ZERO_BYTES;                                // int[NN] (written by fine)
constexpr size_t OFF_DIS  = OFF_CNT  + ALGN((size_t)NN * 4);           // float[NN]
constexpr size_t OFF_ROWP = OFF_DIS  + ALGN((size_t)NN * 4);           // int[NN]
constexpr size_t OFF_BSUM = OFF_ROWP + ALGN((size_t)NN * 4);           // int[256] scan block totals
constexpr size_t OFF_WT   = OFF_BSUM + ALGN(256 * 4);                  // bf16[64][256] W^T stacked
constexpr size_t OFF_CSR  = OFF_WT   + ALGN(16384 * 2);                // int2[NE] final {src, w-bits}
constexpr size_t OFF_H    = OFF_CSR  + ALGN((size_t)NE * 8);           // bf16[4][NN][64] planes x|h1|h2|h3
constexpr size_t OFF_OUT  = OFF_H    + ALGN((size_t)NN * 256 * 2);     // float[NN*FD]
// aliases inside the OUT region (all dead before gemm):
constexpr size_t OFF_CSRT = OFF_OUT;                                   // int2[NE] {src|fine<<17, w}
constexpr size_t OFF_CC   = OFF_CSRT + ALGN((size_t)NE * 8);           // int[NB1*CB] count/scan matrix
static_assert(OFF_CC + (size_t)CCN * 4 - OFF_OUT <= (size_t)NN * FD * 4, "alias overflow");

// ---------------- phase 1: coarse LDS histogram + xcopy/wt streaming ----------------
#define XCB 6250   // NN*64 f32 -> bf16, 4 elems/thread: 6.4M/1024
__global__ __launch_bounds__(256) void coarse_fused_kernel(const int* __restrict__ dst,
                                                           int* __restrict__ cc,
                                                           const float* __restrict__ x,
                                                           bf16* __restrict__ H,
                                                           const float* __restrict__ W,
                                                           bf16* __restrict__ Wt) {
    int b = blockIdx.x;
    if (b < CB) {
        __shared__ int hist[NB1];
        for (int i = threadIdx.x; i < NB1; i += 256) hist[i] = 0;
        __syncthreads();
        int e0 = b * EPB + threadIdx.x;
        #pragma unroll
        for (int i = 0; i < EPB / 256; i++)
            atomicAdd(&hist[dst[e0 + i * 256] >> 8], 1);   // LDS atomic, rare conflicts
        __syncthreads();
        for (int i = threadIdx.x; i < NB1; i += 256)
            cc[(size_t)i * CB + b] = hist[i];              // [bucket][block] matrix
    } else if (b < CB + XCB) {
        // x (f32) -> plane0 (bf16), fully linear stream, 4 elems/thread
        int i = (b - CB) * 256 + threadIdx.x;              // 0 .. NN*64/4-1 exact
        float4 xv = ((const float4*)x)[i];
        bf16 t0 = f2b(xv.x), t1 = f2b(xv.y), t2 = f2b(xv.z), t3 = f2b(xv.w);
        ushort4 o;
        o.x = *(unsigned short*)&t0; o.y = *(unsigned short*)&t1;
        o.z = *(unsigned short*)&t2; o.w = *(unsigned short*)&t3;
        ((ushort4*)H)[i] = o;
    } else {
        int i = (b - CB - XCB) * 256 + threadIdx.x;  // 0..16383
        int n = i & 63, kk = i >> 6;
        Wt[n * 256 + kk] = f2b(W[kk * 64 + n]);
    }
}

// ---------------- scan of the count matrix (block-local scans + block totals) -------
#define SCAN_BLK 256
#define SCAN_ITEMS 8   // 2048 elems per block
__global__ __launch_bounds__(SCAN_BLK) void scan_blocks(int* __restrict__ data,
                                                        int* __restrict__ bsum, int n) {
    __shared__ int lds[SCAN_BLK];
    int t = threadIdx.x, b = blockIdx.x;
    int base = b * SCAN_BLK * SCAN_ITEMS + t * SCAN_ITEMS;
    int v[SCAN_ITEMS];
    int s = 0;
    #pragma unroll
    for (int i = 0; i < SCAN_ITEMS; i++) {
        int idx = base + i;
        v[i] = (idx < n) ? data[idx] : 0;
        s += v[i];
    }
    lds[t] = s;
    __syncthreads();
    for (int off = 1; off < SCAN_BLK; off <<= 1) {
        int x = (t >= off) ? lds[t - off] : 0;
        __syncthreads();
        lds[t] += x;
        __syncthreads();
    }
    int excl = lds[t] - s;
    if (t == SCAN_BLK - 1) bsum[b] = lds[t];   // per-block TOTAL (readers prefix it)
    int run = excl;
    #pragma unroll
    for (int i = 0; i < SCAN_ITEMS; i++) {
        int idx = base + i;
        if (idx < n) data[idx] = run;          // in-place: own range only, reads done
        run += v[i];
    }
}

// ---------------- phase 3: LDS-sorted coarse scatter, coalesced write-out ------------
// R20: computes the 120-entry bsum prefix inline (folded into the sc scan loop).
__global__ __launch_bounds__(256) void scatter2_kernel(const int* __restrict__ src,
                                                       const int* __restrict__ dst,
                                                       const float* __restrict__ ew,
                                                       const int* __restrict__ cc,
                                                       const int* __restrict__ bsum,
                                                       int2* __restrict__ csrt) {
    __shared__ int sc[512];        // bucket counts -> inclusive prefix (padded to 512)
    __shared__ int bp[128];        // bsum inclusive prefix (SCB2=120 entries)
    __shared__ int gdel[NB1];      // global_start - local_start per bucket
    __shared__ int2 stage[EPB];    // block's edges in bucket order
    __shared__ int sdel[EPB];      // per-slot global delta
    int t = threadIdx.x;
    int L = xcd_chunk(blockIdx.x, CB);   // adjacent logical blocks -> same XCD

    sc[t] = 0; sc[t + 256] = 0;
    if (t < 128) bp[t] = (t < SCB2) ? bsum[t] : 0;
    __syncthreads();

    int br[EPB / 256], px[EPB / 256], pw[EPB / 256];
    #pragma unroll
    for (int i = 0; i < EPB / 256; i++) {
        int e = L * EPB + i * 256 + t;
        int d = dst[e];
        int bk = d >> 8;
        int rk = atomicAdd(&sc[bk], 1);            // local rank within (bucket, block)
        br[i] = bk | (rk << 9);                    // bk<512 (9b), rk<2560 (12b)
        px[i] = src[e] | ((d & 255) << 17);        // src<2^17, fine dst bits 17..24
        pw[i] = __float_as_int(ew[e]);
    }
    __syncthreads();

    // inclusive scan of sc[0..511] (+ bp[0..127] folded in), Hillis-Steele
    for (int off = 1; off < 512; off <<= 1) {
        int a0 = (t >= off) ? sc[t - off] : 0;
        int a1 = sc[t + 256 - off];                // t+256 >= 256 >= off always
        int a2 = (off < 128 && t < 128 && t >= off) ? bp[t - off] : 0;
        __syncthreads();
        sc[t] += a0; sc[t + 256] += a1;
        if (off < 128 && t < 128) bp[t] += a2;
        __syncthreads();
    }

    for (int i = t; i < NB1; i += 256) {
        int idx = i * CB + L;
        int k = idx >> 11;
        int gpref = (k > 0) ? bp[k - 1] : 0;
        gdel[i] = cc[idx] + gpref - ((i > 0) ? sc[i - 1] : 0);
    }
    __syncthreads();

    #pragma unroll
    for (int i = 0; i < EPB / 256; i++) {
        int bk = br[i] & 511;
        int rk = br[i] >> 9;
        int slot = ((bk > 0) ? sc[bk - 1] : 0) + rk;
        stage[slot] = make_int2(px[i], pw[i]);
        sdel[slot] = gdel[bk];
    }
    __syncthreads();

    for (int j = t; j < EPB; j += 256)             // coalesced runs out
        csrt[(size_t)(sdel[j] + j)] = stage[j];
}

// ---------------- phase 4: per-bucket fine sort + rowp/cnts/dis emission ------------
// R20: computes bucket bounds from raw cc + inline bsum prefix.
__global__ __launch_bounds__(256) void fine_kernel(const int* __restrict__ cc,
                                                   const int* __restrict__ bsum,
                                                   const int2* __restrict__ csrt,
                                                   int2* __restrict__ csr,
                                                   int* __restrict__ rowp,
                                                   int* __restrict__ cnts,
                                                   float* __restrict__ dis) {
    __shared__ int hist[256];
    __shared__ float degw[256];
    __shared__ int pref[256];
    __shared__ int fcur[256];
    __shared__ int bp[128];
    __shared__ int bounds[2];
    int b = blockIdx.x;
    int t = threadIdx.x;
    hist[t] = 0; degw[t] = 0.f;
    if (t < 128) bp[t] = (t < SCB2) ? bsum[t] : 0;
    __syncthreads();
    for (int off = 1; off < 128; off <<= 1) {
        int x = (t < 128 && t >= off) ? bp[t - off] : 0;
        __syncthreads();
        if (t < 128) bp[t] += x;
        __syncthreads();
    }
    if (t == 0) {
        int i0 = b * CB, k0 = i0 >> 11;
        bounds[0] = cc[i0] + ((k0 > 0) ? bp[k0 - 1] : 0);
        if (b == NB1 - 1) bounds[1] = NE;
        else {
            int i1 = (b + 1) * CB, k1 = i1 >> 11;
            bounds[1] = cc[i1] + ((k1 > 0) ? bp[k1 - 1] : 0);
        }
    }
    __syncthreads();
    int base = bounds[0];
    int cnt = bounds[1] - base;

    for (int j = t; j < cnt; j += 256) {
        int2 e = csrt[base + j];
        int f = e.x >> 17;
        atomicAdd(&hist[f], 1);
        atomicAdd(&degw[f], __int_as_float(e.y));  // deg = sum of raw w per dst row
    }
    __syncthreads();
    int hv = hist[t];
    pref[t] = hv;
    __syncthreads();
    for (int off = 1; off < 256; off <<= 1) {
        int x = (t >= off) ? pref[t - off] : 0;
        __syncthreads();
        pref[t] += x;
        __syncthreads();
    }
    int ex = pref[t] - hv;                  // exclusive fine prefix
    fcur[t] = ex;
    int node = b * 256 + t;
    if (node < NN) {
        rowp[node] = base + ex;
        cnts[node] = hv;
        float s = degw[t];
        dis[node] = (s > 0.f) ? rsqrtf(s) : 0.f;
    }
    __syncthreads();
    for (int j = t; j < cnt; j += 256) {    // 2nd read hits L2 (33KB slice)
        int2 e = csrt[base + j];
        int f = e.x >> 17;
        int pos = atomicAdd(&fcur[f], 1);   // LDS atomic
        csr[base + pos] = make_int2(e.x & 0x1FFFF, e.y);
    }
}

// ---------------- hop: wide-vector gather, 2 rows per wave, plane layout ------------
// hin/hout are planes [NN][64]. FIRST: csr.y holds RAW w -> gather dis[e.x],
// nr = w*dis[src], write back so hops 2/3 read pre-scaled.
template <bool FIRST>
__device__ __forceinline__ void row_accum_gen(const bf16* __restrict__ hin,
                                              int2* cp, int cnt,
                                              const float* __restrict__ dis,
                                              int sub, int fl, float a[8]) {
    if (cnt <= 24) {
        int2 e0 = (sub < cnt) ? cp[sub] : make_int2(0, 0);
        int2 e1 = (8 + sub < cnt) ? cp[8 + sub] : make_int2(0, 0);
        int2 e2 = (16 + sub < cnt) ? cp[16 + sub] : make_int2(0, 0);
        bf16x8 v0 = *(const bf16x8*)(hin + (size_t)e0.x * 64 + fl * 8);
        bf16x8 v1 = *(const bf16x8*)(hin + (size_t)e1.x * 64 + fl * 8);
        bf16x8 v2 = *(const bf16x8*)(hin + (size_t)e2.x * 64 + fl * 8);
        float w0 = __int_as_float(e0.y);
        float w1 = __int_as_float(e1.y);
        float w2 = __int_as_float(e2.y);
        if (FIRST) {
            w0 *= dis[e0.x]; w1 *= dis[e1.x]; w2 *= dis[e2.x];
            if (fl == 0) {
                if (sub < cnt)      cp[sub].y      = __float_as_int(w0);
                if (8 + sub < cnt)  cp[8 + sub].y  = __float_as_int(w1);
                if (16 + sub < cnt) cp[16 + sub].y = __float_as_int(w2);
            }
        }
        #pragma unroll
        for (int i = 0; i < 8; i++)
            a[i] += w0 * b2f_bits(v0[i]) + w1 * b2f_bits(v1[i]) + w2 * b2f_bits(v2[i]);
    } else {
        float b[8] = {0, 0, 0, 0, 0, 0, 0, 0};
        int j = 0;
        for (; j + 16 <= cnt; j += 16) {
            int2 e0 = cp[j + sub];
            int2 e1 = cp[j + 8 + sub];
            bf16x8 v0 = *(const bf16x8*)(hin + (size_t)e0.x * 64 + fl * 8);
            bf16x8 v1 = *(const bf16x8*)(hin + (size_t)e1.x * 64 + fl * 8);
            float w0 = __int_as_float(e0.y);
            float w1 = __int_as_float(e1.y);
            if (FIRST) {
                w0 *= dis[e0.x]; w1 *= dis[e1.x];
                if (fl == 0) {
                    cp[j + sub].y     = __float_as_int(w0);
                    cp[j + 8 + sub].y = __float_as_int(w1);
                }
            }
            #pragma unroll
            for (int i = 0; i < 8; i++) a[i] += w0 * b2f_bits(v0[i]);
            #pragma unroll
            for (int i = 0; i < 8; i++) b[i] += w1 * b2f_bits(v1[i]);
        }
        for (; j < cnt; j += 8) {
            int jj = j + sub;
            int2 e = (jj < cnt) ? cp[jj] : make_int2(0, 0);
            bf16x8 v = *(const bf16x8*)(hin + (size_t)e.x * 64 + fl * 8);
            float w = __int_as_float(e.y);
            if (FIRST) {
                w *= dis[e.x];
                if (fl == 0 && jj < cnt) cp[jj].y = __float_as_int(w);
            }
            #pragma unroll
            for (int i = 0; i < 8; i++) a[i] += w * b2f_bits(v[i]);
        }
        #pragma unroll
        for (int i = 0; i < 8; i++) a[i] += b[i];
    }
}

// 2-row hop (proven 28-VGPR structure)
template <bool FIRST>
__global__ __launch_bounds__(256) void hop_kernel(const bf16* __restrict__ hin,  // plane k-1
                                                  bf16* __restrict__ hout,       // plane k
                                                  const int* __restrict__ rowp,
                                                  const int* __restrict__ cnts,
                                                  int2* __restrict__ csr,
                                                  const float* __restrict__ dis) {
    int pair = blockIdx.x * 4 + (threadIdx.x >> 6);
    int rowA = pair * 2;
    if (rowA >= NN) return;
    rowA = __builtin_amdgcn_readfirstlane(rowA);
    int rowB = rowA + 1;                     // NN even -> always valid
    int lane = threadIdx.x & 63;
    int sub = lane >> 3;   // edge slot 0..7
    int fl = lane & 7;     // feature octet 0..7

    int stA = rowp[rowA], cnA = cnts[rowA];
    int stB = rowp[rowB], cnB = cnts[rowB];
    float drA = dis[rowA], drB = dis[rowB];
    int2* cpA = csr + stA;
    int2* cpB = csr + stB;

    float a[8] = {0, 0, 0, 0, 0, 0, 0, 0};
    float c[8] = {0, 0, 0, 0, 0, 0, 0, 0};

    if (cnA <= 24 && cnB <= 24) {
        int2 eA0 = (sub < cnA) ? cpA[sub] : make_int2(0, 0);
        int2 eA1 = (8 + sub < cnA) ? cpA[8 + sub] : make_int2(0, 0);
        int2 eA2 = (16 + sub < cnA) ? cpA[16 + sub] : make_int2(0, 0);
        int2 eB0 = (sub < cnB) ? cpB[sub] : make_int2(0, 0);
        int2 eB1 = (8 + sub < cnB) ? cpB[8 + sub] : make_int2(0, 0);
        int2 eB2 = (16 + sub < cnB) ? cpB[16 + sub] : make_int2(0, 0);
        const bf16* hf = hin + fl * 8;
        bf16x8 vA0 = *(const bf16x8*)(hf + (size_t)eA0.x * 64);
        bf16x8 vA1 = *(const bf16x8*)(hf + (size_t)eA1.x * 64);
        bf16x8 vA2 = *(const bf16x8*)(hf + (size_t)eA2.x * 64);
        bf16x8 vB0 = *(const bf16x8*)(hf + (size_t)eB0.x * 64);
        bf16x8 vB1 = *(const bf16x8*)(hf + (size_t)eB1.x * 64);
        bf16x8 vB2 = *(const bf16x8*)(hf + (size_t)eB2.x * 64);
        float wA0 = __int_as_float(eA0.y);
        float wA1 = __int_as_float(eA1.y);
        float wA2 = __int_as_float(eA2.y);
        float wB0 = __int_as_float(eB0.y);
        float wB1 = __int_as_float(eB1.y);
        float wB2 = __int_as_float(eB2.y);
        if (FIRST) {
            wA0 *= dis[eA0.x]; wA1 *= dis[eA1.x]; wA2 *= dis[eA2.x];
            wB0 *= dis[eB0.x]; wB1 *= dis[eB1.x]; wB2 *= dis[eB2.x];
            if (fl == 0) {
                if (sub < cnA)      cpA[sub].y      = __float_as_int(wA0);
                if (8 + sub < cnA)  cpA[8 + sub].y  = __float_as_int(wA1);
                if (16 + sub < cnA) cpA[16 + sub].y = __float_as_int(wA2);
                if (sub < cnB)      cpB[sub].y      = __float_as_int(wB0);
                if (8 + sub < cnB)  cpB[8 + sub].y  = __float_as_int(wB1);
                if (16 + sub < cnB) cpB[16 + sub].y = __float_as_int(wB2);
            }
        }
        #pragma unroll
        for (int i = 0; i < 8; i++) {
            a[i] = wA0 * b2f_bits(vA0[i]) + wA1 * b2f_bits(vA1[i]) + wA2 * b2f_bits(vA2[i]);
            c[i] = wB0 * b2f_bits(vB0[i]) + wB1 * b2f_bits(vB1[i]) + wB2 * b2f_bits(vB2[i]);
        }
    } else {
        row_accum_gen<FIRST>(hin, cpA, cnA, dis, sub, fl, a);
        row_accum_gen<FIRST>(hin, cpB, cnB, dis, sub, fl, c);
    }

    #pragma unroll
    for (int i = 0; i < 8; i++) { a[i] += __shfl_xor(a[i], 8);  c[i] += __shfl_xor(c[i], 8); }
    #pragma unroll
    for (int i = 0; i < 8; i++) { a[i] += __shfl_xor(a[i], 16); c[i] += __shfl_xor(c[i], 16); }
    #pragma unroll
    for (int i = 0; i < 8; i++) { a[i] += __shfl_xor(a[i], 32); c[i] += __shfl_xor(c[i], 32); }

    if (sub == 0) {
        bf16x8 ovA, ovB;
        #pragma unroll
        for (int i = 0; i < 8; i++) {
            bf16 tA = f2b(a[i] * drA);
            bf16 tB = f2b(c[i] * drB);
            ovA[i] = *(short*)&tA;
            ovB[i] = *(short*)&tB;
        }
        *(bf16x8*)(hout + (size_t)rowA * 64 + fl * 8) = ovA;
        *(bf16x8*)(hout + (size_t)rowB * 64 + fl * 8) = ovB;
    }
}

// ---------------- persistent-wave GEMM: out = H[NN x 256] @ Wcat[256 x 64] + bias ----
// R15 structure exactly (R21: stats fusion removed — it evicted B from registers).
#define GWAVES 1024
#define NT (NN / 16)   // 6250 row-tiles

__global__ __launch_bounds__(256, 1) void gemm_kernel(const bf16* __restrict__ H,
                                                      const bf16* __restrict__ Wt,
                                                      const float* __restrict__ bias,
                                                      float* __restrict__ outb) {
    int wave = threadIdx.x >> 6;
    int lane = threadIdx.x & 63;
    int m = lane & 15, q = lane >> 4;
    int w = blockIdx.x * 4 + wave;

    // B register-resident: all 4 col-tiles x 8 k-slices
    bf16x8 B[4][8];
    #pragma unroll
    for (int n = 0; n < 4; n++) {
        const bf16* brow = Wt + (size_t)(n * 16 + m) * 256 + q * 8;
        #pragma unroll
        for (int ks = 0; ks < 8; ks++) B[n][ks] = *(const bf16x8*)(brow + ks * 32);
    }
    float bv[4];
    #pragma unroll
    for (int n = 0; n < 4; n++) bv[n] = bias[n * 16 + m];

    if (w >= NT) return;

    bf16x8 A0[8], A1[8];

    #define LOADA(dst_, t_)                                                      \
        {                                                                        \
            _Pragma("unroll")                                                    \
            for (int ks = 0; ks < 8; ks++)                                       \
                dst_[ks] = *(const bf16x8*)(H +                                  \
                    ((size_t)(ks >> 1) * NN + (size_t)((t_)*16 + m)) * 64 +      \
                    (ks & 1) * 32 + q * 8);                                      \
        }

    #define COMP(src_, t_)                                                   \
        {                                                                    \
            _Pragma("unroll")                                                \
            for (int n = 0; n < 4; n++) {                                    \
                f32x4 acc = {0.f, 0.f, 0.f, 0.f};                            \
                _Pragma("unroll")                                            \
                for (int ks = 0; ks < 8; ks++)                               \
                    acc = __builtin_amdgcn_mfma_f32_16x16x32_bf16(           \
                        src_[ks], B[n][ks], acc, 0, 0, 0);                   \
                _Pragma("unroll")                                            \
                for (int r = 0; r < 4; r++)                                  \
                    outb[(size_t)((t_)*16 + q * 4 + r) * 64 + n * 16 + m] =  \
                        acc[r] + bv[n];                                      \
            }                                                                \
        }

    int t = w;
    LOADA(A0, t)
    while (true) {
        int t1 = t + GWAVES;
        if (t1 < NT) LOADA(A1, t1)
        COMP(A0, t)
        if (t1 >= NT) return;
        int t2 = t1 + GWAVES;
        if (t2 < NT) LOADA(A0, t2)
        COMP(A1, t1)
        if (t2 >= NT) return;
        t = t2;
    }
    #undef LOADA
    #undef COMP
}

// ---------------- GraphNorm: single-pass sum+sumsq ----------------
#define CH 32
#define STAT_WAVES ((NN + CH - 1) / CH)
#define STAT_BLOCKS ((STAT_WAVES * 64 + 255) / 256)

__global__ __launch_bounds__(256) void stats_kernel(const float* __restrict__ outb,
                                                    const int* __restrict__ batch,
                                                    float* __restrict__ gsum,
                                                    float* __restrict__ gssq,
                                                    float* __restrict__ gcnt) {
    int wid = (blockIdx.x * 256 + threadIdx.x) >> 6;
    int lane = threadIdx.x & 63;
    int n0 = wid * CH;
    if (n0 >= NN) return;
    int n1 = min(n0 + CH, NN);
    int g0 = batch[n0];
    if (n1 == n0 + CH && batch[n1 - 1] == g0) {
        float s = 0.f, s2 = 0.f;
        #pragma unroll
        for (int i = 0; i < CH; i++) {
            float v = outb[(size_t)(n0 + i) * 64 + lane];
            s += v; s2 += v * v;
        }
        atomicAdd(&gsum[g0 * 64 + lane], s);
        atomicAdd(&gssq[g0 * 64 + lane], s2);
        if (lane == 0) atomicAdd(&gcnt[g0], (float)CH);
    } else {
        int cur = g0; float s = 0.f, s2 = 0.f; int cl = 0;
        for (int i = n0; i < n1; i++) {
            int g = batch[i];
            if (g != cur) {
                atomicAdd(&gsum[cur * 64 + lane], s);
                atomicAdd(&gssq[cur * 64 + lane], s2);
                if (lane == 0) atomicAdd(&gcnt[cur], (float)cl);
                s = 0.f; s2 = 0.f; cl = 0; cur = g;
            }
            float v = outb[(size_t)i * 64 + lane];
            s += v; s2 += v * v; cl++;
        }
        atomicAdd(&gsum[cur * 64 + lane], s);
        atomicAdd(&gssq[cur * 64 + lane], s2);
        if (lane == 0) atomicAdd(&gcnt[cur], (float)cl);
    }
}

// mm/rstd from raw stats: mm = mean*ms; var = E[v^2]-2*mm*E[v]+mm^2
__device__ __forceinline__ void graph_mr(const float* gsum, const float* gssq,
                                         const float* gcnt, int g, int lane, float ms,
                                         float& mm, float& r) {
    float c = fmaxf(gcnt[g], 1.f);
    float mean = gsum[g * 64 + lane] / c;
    float msq = gssq[g * 64 + lane] / c;
    mm = mean * ms;
    float var = fmaxf(msq - 2.f * mm * mean + mm * mm, 0.f);
    r = rsqrtf(var + EPSV);
}

// normalize + residual + relu + write h_emb + pool accumulation
__global__ __launch_bounds__(256) void final_kernel(const float* __restrict__ outb,
                                                    const int* __restrict__ batch,
                                                    const float* __restrict__ xg,
                                                    const float* __restrict__ gsum,
                                                    const float* __restrict__ gssq,
                                                    const float* __restrict__ gcnt,
                                                    const float* __restrict__ gw_,
                                                    const float* __restrict__ gb_,
                                                    const float* __restrict__ ms_,
                                                    float* __restrict__ psum,
                                                    int* __restrict__ pmax,
                                                    float* __restrict__ hemb) {
    int wid = (blockIdx.x * 256 + threadIdx.x) >> 6;
    int lane = threadIdx.x & 63;
    int n0 = wid * CH;
    if (n0 >= NN) return;
    int n1 = min(n0 + CH, NN);
    float gw = gw_[lane], gb = gb_[lane], ms = ms_[lane];
    int g0 = batch[n0];
    if (n1 == n0 + CH && batch[n1 - 1] == g0) {
        float m, r;
        graph_mr(gsum, gssq, gcnt, g0, lane, ms, m, r);
        float ps = 0.f, pm = 0.f;
        #pragma unroll
        for (int i = 0; i < CH; i++) {
            size_t idx = (size_t)(n0 + i) * 64 + lane;
            float hn = gw * (outb[idx] - m) * r + gb;
            float he = hn + xg[idx];
            he = he > 0.f ? he : 0.f;
            hemb[idx] = he;
            ps += he;
            pm = fmaxf(pm, he);
        }
        atomicAdd(&psum[g0 * 64 + lane], ps);
        atomicMax(&pmax[g0 * 64 + lane], __float_as_int(pm));
    } else {
        int cur = g0;
        float m, r;
        graph_mr(gsum, gssq, gcnt, cur, lane, ms, m, r);
        float ps = 0.f, pm = 0.f;
        for (int i = n0; i < n1; i++) {
            int g = batch[i];
            if (g != cur) {
                atomicAdd(&psum[cur * 64 + lane], ps);
                atomicMax(&pmax[cur * 64 + lane], __float_as_int(pm));
                ps = 0.f; pm = 0.f; cur = g;
                graph_mr(gsum, gssq, gcnt, cur, lane, ms, m, r);
            }
            size_t idx = (size_t)i * 64 + lane;
            float hn = gw * (outb[idx] - m) * r + gb;
            float he = hn + xg[idx];
            he = he > 0.f ? he : 0.f;
            hemb[idx] = he;
            ps += he;
            pm = fmaxf(pm, he);
        }
        atomicAdd(&psum[cur * 64 + lane], ps);
        atomicMax(&pmax[cur * 64 + lane], __float_as_int(pm));
    }
}

__global__ __launch_bounds__(256) void pool_kernel(const float* __restrict__ psum,
                                                   const int* __restrict__ pmax,
                                                   const float* __restrict__ gcnt,
                                                   float* __restrict__ flat) {
    int i = blockIdx.x * 256 + threadIdx.x;
    if (i >= NG * FD) return;
    int g = i >> 6, f = i & 63;
    float c = fmaxf(gcnt[g], 1.f);
    flat[(size_t)g * 128 + f] = psum[i] / c;
    flat[(size_t)g * 128 + 64 + f] = __int_as_float(pmax[i]);
}

// ---------------- launch ----------------
extern "C" void kernel_launch(void* const* d_in, const int* in_sizes, int n_in,
                              void* d_out, int out_size, void* d_ws, size_t ws_size,
                              hipStream_t stream) {
    const float* x = (const float*)d_in[0];
    const int* ei = (const int*)d_in[1];
    const int* batch = (const int*)d_in[2];
    const float* ew = (const float*)d_in[3];
    const float* W = (const float*)d_in[4];   // [4,64,64]
    const float* bias = (const float*)d_in[5];
    const float* gnw = (const float*)d_in[6];
    const float* gnb = (const float*)d_in[7];
    const float* gms = (const float*)d_in[8];

    const int* src = ei;
    const int* dst = ei + NE;

    char* ws = (char*)d_ws;
    float* gsum = (float*)(ws + OFF_GSUM);
    float* gssq = (float*)(ws + OFF_GSSQ);
    float* gcnt = (float*)(ws + OFF_GCNT);
    float* psum = (float*)(ws + OFF_PSUM);
    int* pmax = (int*)(ws + OFF_PMAX);
    int* cnts = (int*)(ws + OFF_CNT);
    float* dis = (float*)(ws + OFF_DIS);
    int* rowp = (int*)(ws + OFF_ROWP);
    int* bsum = (int*)(ws + OFF_BSUM);
    bf16* Wt = (bf16*)(ws + OFF_WT);
    int2* csr = (int2*)(ws + OFF_CSR);
    bf16* H = (bf16*)(ws + OFF_H);           // plane k at H + k*NN*64
    float* outb = (float*)(ws + OFF_OUT);
    int2* csrt = (int2*)(ws + OFF_CSRT);
    int* cc = (int*)(ws + OFF_CC);

    float* hemb = (float*)d_out;
    float* flat = hemb + (size_t)NN * FD;

    hipMemsetAsync(d_ws, 0, ZERO_BYTES, stream);

    const size_t PL = (size_t)NN * 64;   // plane stride (bf16 elems)
    const int HOPB = (NN / 2 + 3) / 4;   // 2 rows/wave, 4 waves/block
    const int GFB = (NG * FD + 255) / 256;

    coarse_fused_kernel<<<CB + XCB + 64, 256, 0, stream>>>(dst, cc, x, H, W, Wt);
    scan_blocks<<<SCB2, 256, 0, stream>>>(cc, bsum, CCN);
    scatter2_kernel<<<CB, 256, 0, stream>>>(src, dst, ew, cc, bsum, csrt);
    fine_kernel<<<NB1, 256, 0, stream>>>(cc, bsum, csrt, csr, rowp, cnts, dis);

    hop_kernel<true><<<HOPB, 256, 0, stream>>>(H, H + PL, rowp, cnts, csr, dis);              // h1 (+rescale)
    hop_kernel<false><<<HOPB, 256, 0, stream>>>(H + PL, H + 2 * PL, rowp, cnts, csr, dis);    // h2
    hop_kernel<false><<<HOPB, 256, 0, stream>>>(H + 2 * PL, H + 3 * PL, rowp, cnts, csr, dis);// h3

    gemm_kernel<<<GWAVES / 4, 256, 0, stream>>>(H, Wt, bias, outb);

    stats_kernel<<<STAT_BLOCKS, 256, 0, stream>>>(outb, batch, gsum, gssq, gcnt);
    final_kernel<<<STAT_BLOCKS, 256, 0, stream>>>(outb, batch, x, gsum, gssq, gcnt,
                                                  gnw, gnb, gms, psum, pmax, hemb);
    pool_kernel<<<GFB, 256, 0, stream>>>(psum, pmax, gcnt, flat);
}